// Round 1
// baseline (15383.733 us; speedup 1.0000x reference)
//
#include <hip/hip_runtime.h>

#define NPIX (512 * 512)
#define NC 21

static inline int cdiv_l(long a, int b) { return (int)((a + b - 1) / b); }

// Q = softmax(-u) per pixel
__global__ void softmax_init_k(const float* __restrict__ u, float* __restrict__ Q, int N) {
    int n = blockIdx.x * blockDim.x + threadIdx.x;
    if (n >= N) return;
    const float* up = u + (size_t)n * NC;
    float v[NC];
    float mx = -1e30f;
#pragma unroll
    for (int c = 0; c < NC; c++) { v[c] = -up[c]; mx = fmaxf(mx, v[c]); }
    float s = 0.f;
#pragma unroll
    for (int c = 0; c < NC; c++) { v[c] = __expf(v[c] - mx); s += v[c]; }
    float inv = 1.f / s;
    float* qp = Q + (size_t)n * NC;
#pragma unroll
    for (int c = 0; c < NC; c++) qp[c] = v[c] * inv;
}

// Q = softmax(-u + 10*bi + 3*sp)   (pairwise = -(10*bi+3*sp); logits = -u - pairwise)
__global__ void update_k(const float* __restrict__ u, const float* __restrict__ bi,
                         const float* __restrict__ sp, float* __restrict__ Q, int N) {
    int n = blockIdx.x * blockDim.x + threadIdx.x;
    if (n >= N) return;
    size_t base = (size_t)n * NC;
    float v[NC];
    float mx = -1e30f;
#pragma unroll
    for (int c = 0; c < NC; c++) {
        float x = -u[base + c] + 10.f * bi[base + c] + 3.f * sp[base + c];
        v[c] = x;
        mx = fmaxf(mx, x);
    }
    float s = 0.f;
#pragma unroll
    for (int c = 0; c < NC; c++) { v[c] = __expf(v[c] - mx); s += v[c]; }
    float inv = 1.f / s;
#pragma unroll
    for (int c = 0; c < NC; c++) Q[base + c] = v[c] * inv;
}

// C=1 splat of ones: val[os[t]] += ws[t] over all N*(d+1) entries
__global__ void splat_ones_k(const float* __restrict__ ws, const int* __restrict__ os,
                             float* __restrict__ val, int NK) {
    int t = blockIdx.x * blockDim.x + threadIdx.x;
    if (t >= NK) return;
    atomicAdd(&val[os[t]], ws[t]);
}

// C=1 blur along one lattice direction; row 0 is the zero pad row
__global__ void blur1_k(const float* __restrict__ vin, float* __restrict__ vout,
                        const int* __restrict__ nbr, int M) {
    int t = blockIdx.x * blockDim.x + threadIdx.x;
    if (t > M) return;
    if (t == 0) { vout[0] = 0.f; return; }
    int n1 = nbr[(size_t)(t - 1) * 2 + 0];
    int n2 = nbr[(size_t)(t - 1) * 2 + 1];
    vout[t] = vin[t] + 0.5f * (vin[n1] + vin[n2]);
}

// C=1 slice -> norm = 1/(sqrt(alpha * sum_j ws*val[os]) + 1e-20)
__global__ void slice_norm_k(const float* __restrict__ ws, const int* __restrict__ os,
                             const float* __restrict__ val, float* __restrict__ nrm,
                             int N, int K, float alpha) {
    int n = blockIdx.x * blockDim.x + threadIdx.x;
    if (n >= N) return;
    float s = 0.f;
    for (int j = 0; j < K; j++) s += ws[(size_t)n * K + j] * val[os[(size_t)n * K + j]];
    nrm[n] = 1.f / (sqrtf(alpha * s) + 1e-20f);
}

// splat of (Q * nrm) for channels [c0, c0+CB): one thread per (n,j) entry
__global__ void splatQ_k(const float* __restrict__ Q, const float* __restrict__ nrm,
                         const float* __restrict__ ws, const int* __restrict__ os,
                         float* __restrict__ val, int N, int K, int c0, int CB) {
    int t = blockIdx.x * blockDim.x + threadIdx.x;
    if (t >= N * K) return;
    int n = t / K;
    float w = ws[t] * nrm[n];
    float* vp = val + (size_t)os[t] * CB;
    const float* qp = Q + (size_t)n * NC + c0;
    for (int c = 0; c < CB; c++) atomicAdd(&vp[c], w * qp[c]);
}

// CB-channel blur along one direction; thread per (row, channel)
__global__ void blurC_k(const float* __restrict__ vin, float* __restrict__ vout,
                        const int* __restrict__ nbr, int M, int CB) {
    int t = blockIdx.x * blockDim.x + threadIdx.x;
    int total = (M + 1) * CB;
    if (t >= total) return;
    int m = t / CB;
    int c = t - m * CB;
    if (m == 0) { vout[t] = 0.f; return; }
    int n1 = nbr[(size_t)(m - 1) * 2 + 0];
    int n2 = nbr[(size_t)(m - 1) * 2 + 1];
    vout[t] = vin[t] + 0.5f * (vin[(size_t)n1 * CB + c] + vin[(size_t)n2 * CB + c]);
}

// slice channels [c0, c0+CB) -> out[n, c0+c] = alpha * nrm[n] * sum_j ws*val[os][c]
__global__ void sliceC_k(const float* __restrict__ ws, const int* __restrict__ os,
                         const float* __restrict__ val, const float* __restrict__ nrm,
                         float* __restrict__ out, int N, int K, int c0, int CB, float alpha) {
    int n = blockIdx.x * blockDim.x + threadIdx.x;
    if (n >= N) return;
    float acc[NC];
#pragma unroll
    for (int c = 0; c < NC; c++) acc[c] = 0.f;
    for (int j = 0; j < K; j++) {
        float w = ws[(size_t)n * K + j];
        const float* vp = val + (size_t)os[(size_t)n * K + j] * CB;
#pragma unroll
        for (int c = 0; c < NC; c++)
            if (c < CB) acc[c] += w * vp[c];
    }
    float sc = alpha * nrm[n];
    float* op = out + (size_t)n * NC + c0;
#pragma unroll
    for (int c = 0; c < NC; c++)
        if (c < CB) op[c] = sc * acc[c];
}

extern "C" void kernel_launch(void* const* d_in, const int* in_sizes, int n_in,
                              void* d_out, int out_size, void* d_ws, size_t ws_size,
                              hipStream_t stream) {
    const float* unary  = (const float*)d_in[0];
    const float* ws_bi  = (const float*)d_in[1];
    const float* ws_sp  = (const float*)d_in[2];
    const int*   os_bi  = (const int*)d_in[3];
    const int*   os_sp  = (const int*)d_in[4];
    const int*   nbr_bi = (const int*)d_in[5];
    const int*   nbr_sp = (const int*)d_in[6];
    float* Q = (float*)d_out;

    const int N = NPIX, Kbi = 6, Ksp = 3;
    const int Mbi = in_sizes[5] / (Kbi * 2);   // nbr_bi is [6, Mbi, 2]
    const int Msp = in_sizes[6] / (Ksp * 2);   // nbr_sp is [3, Msp, 2]
    const float alpha_bi = 32.f / 33.f;        // 1/(1+2^-5)
    const float alpha_sp = 0.8f;               // 1/(1+2^-2)

    // ---- workspace layout (floats) ----
    float* base = (float*)d_ws;
    size_t off = 0;
    auto alloc = [&](size_t nf) { float* p = base + off; off += (nf + 3) & ~(size_t)3; return p; };
    float* bi_out = alloc((size_t)N * NC);
    float* sp_out = alloc((size_t)N * NC);
    float* nrm_bi = alloc(N);
    float* nrm_sp = alloc(N);
    float* vspA   = alloc((size_t)(Msp + 1) * NC);
    float* vspB   = alloc((size_t)(Msp + 1) * NC);
    size_t avail_f = ws_size / 4;
    size_t remain = (avail_f > off + 16) ? (avail_f - off - 16) : 0;
    int CB = (int)(remain / (2 * (size_t)(Mbi + 1)));   // channels per bilateral chunk
    if (CB > NC) CB = NC;
    if (CB < 1) CB = 1;
    float* vbiA = alloc((size_t)(Mbi + 1) * CB);
    float* vbiB = alloc((size_t)(Mbi + 1) * CB);

    const int B = 256;

    // 1) Q = softmax(-u)
    softmax_init_k<<<cdiv_l(N, B), B, 0, stream>>>(unary, Q, N);

    // 2) bilateral normalization (C=1 lattice on ones)
    hipMemsetAsync(vbiA, 0, (size_t)(Mbi + 1) * sizeof(float), stream);
    splat_ones_k<<<cdiv_l((long)N * Kbi, B), B, 0, stream>>>(ws_bi, os_bi, vbiA, N * Kbi);
    {
        float* s = vbiA; float* d = vbiB;
        for (int j = 0; j < Kbi; j++) {
            blur1_k<<<cdiv_l(Mbi + 1, B), B, 0, stream>>>(s, d, nbr_bi + (size_t)j * Mbi * 2, Mbi);
            float* t = s; s = d; d = t;
        }
        slice_norm_k<<<cdiv_l(N, B), B, 0, stream>>>(ws_bi, os_bi, s, nrm_bi, N, Kbi, alpha_bi);
    }

    // 3) spatial normalization
    hipMemsetAsync(vspA, 0, (size_t)(Msp + 1) * sizeof(float), stream);
    splat_ones_k<<<cdiv_l((long)N * Ksp, B), B, 0, stream>>>(ws_sp, os_sp, vspA, N * Ksp);
    {
        float* s = vspA; float* d = vspB;
        for (int j = 0; j < Ksp; j++) {
            blur1_k<<<cdiv_l(Msp + 1, B), B, 0, stream>>>(s, d, nbr_sp + (size_t)j * Msp * 2, Msp);
            float* t = s; s = d; d = t;
        }
        slice_norm_k<<<cdiv_l(N, B), B, 0, stream>>>(ws_sp, os_sp, s, nrm_sp, N, Ksp, alpha_sp);
    }

    // 4) mean-field iterations
    for (int it = 0; it < 5; it++) {
        // bilateral filtering of Q*nrm_bi, channel-chunked
        for (int c0 = 0; c0 < NC; c0 += CB) {
            int cb = (NC - c0 < CB) ? (NC - c0) : CB;
            hipMemsetAsync(vbiA, 0, (size_t)(Mbi + 1) * cb * sizeof(float), stream);
            splatQ_k<<<cdiv_l((long)N * Kbi, B), B, 0, stream>>>(Q, nrm_bi, ws_bi, os_bi, vbiA,
                                                                 N, Kbi, c0, cb);
            float* s = vbiA; float* d = vbiB;
            for (int j = 0; j < Kbi; j++) {
                blurC_k<<<cdiv_l((long)(Mbi + 1) * cb, B), B, 0, stream>>>(
                    s, d, nbr_bi + (size_t)j * Mbi * 2, Mbi, cb);
                float* t = s; s = d; d = t;
            }
            sliceC_k<<<cdiv_l(N, B), B, 0, stream>>>(ws_bi, os_bi, s, nrm_bi, bi_out,
                                                     N, Kbi, c0, cb, alpha_bi);
        }
        // spatial filtering of Q*nrm_sp (single chunk, buffers hold full NC)
        hipMemsetAsync(vspA, 0, (size_t)(Msp + 1) * NC * sizeof(float), stream);
        splatQ_k<<<cdiv_l((long)N * Ksp, B), B, 0, stream>>>(Q, nrm_sp, ws_sp, os_sp, vspA,
                                                             N, Ksp, 0, NC);
        {
            float* s = vspA; float* d = vspB;
            for (int j = 0; j < Ksp; j++) {
                blurC_k<<<cdiv_l((long)(Msp + 1) * NC, B), B, 0, stream>>>(
                    s, d, nbr_sp + (size_t)j * Msp * 2, Msp, NC);
                float* t = s; s = d; d = t;
            }
            sliceC_k<<<cdiv_l(N, B), B, 0, stream>>>(ws_sp, os_sp, s, nrm_sp, sp_out,
                                                     N, Ksp, 0, NC, alpha_sp);
        }
        // Q = softmax(-u + 10*bi + 3*sp)
        update_k<<<cdiv_l(N, B), B, 0, stream>>>(unary, bi_out, sp_out, Q, N);
    }
}

// Round 2
// 4828.926 us; speedup vs baseline: 3.1857x; 3.1857x over previous
//
#include <hip/hip_runtime.h>

#define NPIX (512 * 512)
#define NC 21
#define SCAN_CHUNK 2048
#define SCAN_T 256

static inline int cdiv_l(long a, int b) { return (int)((a + b - 1) / b); }

// ---------------- softmax kernels ----------------
__global__ void softmax_init_k(const float* __restrict__ u, float* __restrict__ Q, int N) {
    int n = blockIdx.x * blockDim.x + threadIdx.x;
    if (n >= N) return;
    const float* up = u + (size_t)n * NC;
    float v[NC];
    float mx = -1e30f;
#pragma unroll
    for (int c = 0; c < NC; c++) { v[c] = -up[c]; mx = fmaxf(mx, v[c]); }
    float s = 0.f;
#pragma unroll
    for (int c = 0; c < NC; c++) { v[c] = __expf(v[c] - mx); s += v[c]; }
    float inv = 1.f / s;
    float* qp = Q + (size_t)n * NC;
#pragma unroll
    for (int c = 0; c < NC; c++) qp[c] = v[c] * inv;
}

__global__ void update_k(const float* __restrict__ u, const float* __restrict__ bi,
                         const float* __restrict__ sp, float* __restrict__ Q, int N) {
    int n = blockIdx.x * blockDim.x + threadIdx.x;
    if (n >= N) return;
    size_t base = (size_t)n * NC;
    float v[NC];
    float mx = -1e30f;
#pragma unroll
    for (int c = 0; c < NC; c++) {
        float x = -u[base + c] + 10.f * bi[base + c] + 3.f * sp[base + c];
        v[c] = x;
        mx = fmaxf(mx, x);
    }
    float s = 0.f;
#pragma unroll
    for (int c = 0; c < NC; c++) { v[c] = __expf(v[c] - mx); s += v[c]; }
    float inv = 1.f / s;
#pragma unroll
    for (int c = 0; c < NC; c++) Q[base + c] = v[c] * inv;
}

// ---------------- CSR build: histogram -> scan -> scatter ----------------
__global__ void hist_k(const int* __restrict__ os, int* __restrict__ count, int NK) {
    int t = blockIdx.x * blockDim.x + threadIdx.x;
    if (t < NK) atomicAdd(&count[os[t]], 1);
}

// per-block sums of count[] in chunks of SCAN_CHUNK
__global__ void scan1_k(const int* __restrict__ count, int* __restrict__ bsum, int L) {
    __shared__ int s[SCAN_T];
    int base = blockIdx.x * SCAN_CHUNK;
    int tsum = 0;
    for (int j = threadIdx.x; j < SCAN_CHUNK; j += SCAN_T) {
        int i = base + j;
        tsum += (i < L) ? count[i] : 0;
    }
    s[threadIdx.x] = tsum; __syncthreads();
    for (int o = SCAN_T / 2; o > 0; o >>= 1) {
        if (threadIdx.x < o) s[threadIdx.x] += s[threadIdx.x + o];
        __syncthreads();
    }
    if (threadIdx.x == 0) bsum[blockIdx.x] = s[0];
}

// single-block exclusive scan of bsum[0..nb); also writes off[L] = total
__global__ void scan2_k(int* __restrict__ bsum, int nb, int* __restrict__ off, int L) {
    __shared__ int s[SCAN_T];
    int tid = threadIdx.x;
    int per = (nb + SCAN_T - 1) / SCAN_T;
    int tsum = 0;
    for (int j = 0; j < per; j++) { int i = tid * per + j; if (i < nb) tsum += bsum[i]; }
    s[tid] = tsum; __syncthreads();
    for (int o = 1; o < SCAN_T; o <<= 1) {
        int v = (tid >= o) ? s[tid - o] : 0;
        __syncthreads();
        s[tid] += v;
        __syncthreads();
    }
    int excl = s[tid] - tsum;
    int total = s[SCAN_T - 1];
    int run = excl;
    for (int j = 0; j < per; j++) {
        int i = tid * per + j;
        if (i < nb) { int v = bsum[i]; bsum[i] = run; run += v; }
    }
    if (tid == 0) off[L] = total;
}

// final exclusive scan: off[i] = bsum[blk] + local exclusive prefix
__global__ void scan3_k(const int* __restrict__ count, const int* __restrict__ bsum,
                        int* __restrict__ off, int L) {
    __shared__ int s[SCAN_T];
    const int PER = SCAN_CHUNK / SCAN_T;  // 8
    int tid = threadIdx.x;
    int base = blockIdx.x * SCAN_CHUNK + tid * PER;
    int c[PER];
    int tsum = 0;
#pragma unroll
    for (int j = 0; j < PER; j++) { int i = base + j; c[j] = (i < L) ? count[i] : 0; tsum += c[j]; }
    s[tid] = tsum; __syncthreads();
    for (int o = 1; o < SCAN_T; o <<= 1) {
        int v = (tid >= o) ? s[tid - o] : 0;
        __syncthreads();
        s[tid] += v;
        __syncthreads();
    }
    int run = bsum[blockIdx.x] + s[tid] - tsum;
#pragma unroll
    for (int j = 0; j < PER; j++) {
        int i = base + j;
        if (i < L) off[i] = run;
        run += c[j];
    }
}

__global__ void scatter_k(const int* __restrict__ os, const int* __restrict__ off,
                          int* __restrict__ cur, int* __restrict__ idx, int NK) {
    int t = blockIdx.x * blockDim.x + threadIdx.x;
    if (t >= NK) return;
    int m = os[t];
    int p = off[m] + atomicAdd(&cur[m], 1);
    idx[p] = t;
}

// ---------------- gather-splat (no atomics) ----------------
// C=1 splat of ones: val[m] = sum of ws over row m's contributions
__global__ void splat_gather1_k(const float* __restrict__ ws, const int* __restrict__ off,
                                const int* __restrict__ idx, float* __restrict__ val, int M) {
    int m = blockIdx.x * blockDim.x + threadIdx.x;
    if (m > M) return;
    float s = 0.f;
    if (m > 0) {
        int e0 = off[m], e1 = off[m + 1];
        for (int e = e0; e < e1; e++) s += ws[idx[e]];
    }
    val[m] = s;
}

// CB-channel splat of Q*nrm: one thread per lattice row
__global__ void splat_gatherQ_k(const float* __restrict__ Q, const float* __restrict__ nrm,
                                const float* __restrict__ ws, const int* __restrict__ off,
                                const int* __restrict__ idx, float* __restrict__ val,
                                int M, int K, int c0, int CB) {
    int m = blockIdx.x * blockDim.x + threadIdx.x;
    if (m > M) return;
    float acc[NC];
#pragma unroll
    for (int c = 0; c < NC; c++) acc[c] = 0.f;
    if (m > 0) {
        int e0 = off[m], e1 = off[m + 1];
        for (int e = e0; e < e1; e++) {
            int t = idx[e];
            int n = t / K;
            float w = ws[t] * nrm[n];
            const float* qp = Q + (size_t)n * NC + c0;
#pragma unroll
            for (int c = 0; c < NC; c++)
                if (c < CB) acc[c] += w * qp[c];
        }
    }
    float* vp = val + (size_t)m * CB;
#pragma unroll
    for (int c = 0; c < NC; c++)
        if (c < CB) vp[c] = acc[c];
}

// ---------------- blur ----------------
__global__ void blur1_k(const float* __restrict__ vin, float* __restrict__ vout,
                        const int* __restrict__ nbr, int M) {
    int t = blockIdx.x * blockDim.x + threadIdx.x;
    if (t > M) return;
    if (t == 0) { vout[0] = 0.f; return; }
    int n1 = nbr[(size_t)(t - 1) * 2 + 0];
    int n2 = nbr[(size_t)(t - 1) * 2 + 1];
    vout[t] = vin[t] + 0.5f * (vin[n1] + vin[n2]);
}

__global__ void blurC_k(const float* __restrict__ vin, float* __restrict__ vout,
                        const int* __restrict__ nbr, int M, int CB) {
    int t = blockIdx.x * blockDim.x + threadIdx.x;
    int total = (M + 1) * CB;
    if (t >= total) return;
    int m = t / CB;
    int c = t - m * CB;
    if (m == 0) { vout[t] = 0.f; return; }
    int n1 = nbr[(size_t)(m - 1) * 2 + 0];
    int n2 = nbr[(size_t)(m - 1) * 2 + 1];
    vout[t] = vin[t] + 0.5f * (vin[(size_t)n1 * CB + c] + vin[(size_t)n2 * CB + c]);
}

// ---------------- slice ----------------
__global__ void slice_norm_k(const float* __restrict__ ws, const int* __restrict__ os,
                             const float* __restrict__ val, float* __restrict__ nrm,
                             int N, int K, float alpha) {
    int n = blockIdx.x * blockDim.x + threadIdx.x;
    if (n >= N) return;
    float s = 0.f;
    for (int j = 0; j < K; j++) s += ws[(size_t)n * K + j] * val[os[(size_t)n * K + j]];
    nrm[n] = 1.f / (sqrtf(alpha * s) + 1e-20f);
}

__global__ void sliceC_k(const float* __restrict__ ws, const int* __restrict__ os,
                         const float* __restrict__ val, const float* __restrict__ nrm,
                         float* __restrict__ out, int N, int K, int c0, int CB, float alpha) {
    int n = blockIdx.x * blockDim.x + threadIdx.x;
    if (n >= N) return;
    float acc[NC];
#pragma unroll
    for (int c = 0; c < NC; c++) acc[c] = 0.f;
    for (int j = 0; j < K; j++) {
        float w = ws[(size_t)n * K + j];
        const float* vp = val + (size_t)os[(size_t)n * K + j] * CB;
#pragma unroll
        for (int c = 0; c < NC; c++)
            if (c < CB) acc[c] += w * vp[c];
    }
    float sc = alpha * nrm[n];
    float* op = out + (size_t)n * NC + c0;
#pragma unroll
    for (int c = 0; c < NC; c++)
        if (c < CB) op[c] = sc * acc[c];
}

extern "C" void kernel_launch(void* const* d_in, const int* in_sizes, int n_in,
                              void* d_out, int out_size, void* d_ws, size_t ws_size,
                              hipStream_t stream) {
    const float* unary  = (const float*)d_in[0];
    const float* ws_bi  = (const float*)d_in[1];
    const float* ws_sp  = (const float*)d_in[2];
    const int*   os_bi  = (const int*)d_in[3];
    const int*   os_sp  = (const int*)d_in[4];
    const int*   nbr_bi = (const int*)d_in[5];
    const int*   nbr_sp = (const int*)d_in[6];
    float* Q = (float*)d_out;

    const int N = NPIX, Kbi = 6, Ksp = 3;
    const int Mbi = in_sizes[5] / (Kbi * 2);
    const int Msp = in_sizes[6] / (Ksp * 2);
    const int NKbi = N * Kbi, NKsp = N * Ksp;
    const float alpha_bi = 32.f / 33.f;
    const float alpha_sp = 0.8f;

    // ---- workspace layout (4-byte units) ----
    char* basec = (char*)d_ws;
    size_t off4 = 0;
    auto allocf = [&](size_t nf) { float* p = (float*)basec + off4; off4 += (nf + 3) & ~(size_t)3; return p; };
    auto alloci = [&](size_t ni) { int* p = (int*)basec + off4; off4 += (ni + 3) & ~(size_t)3; return p; };
    float* bi_out = allocf((size_t)N * NC);
    float* sp_out = allocf((size_t)N * NC);
    float* nrm_bi = allocf(N);
    float* nrm_sp = allocf(N);
    float* vspA   = allocf((size_t)(Msp + 1) * NC);
    float* vspB   = allocf((size_t)(Msp + 1) * NC);
    int* off_bi = alloci(Mbi + 2);
    int* cur_bi = alloci(Mbi + 1);   // doubles as histogram count
    int* idx_bi = alloci(NKbi);
    int* off_sp = alloci(Msp + 2);
    int* cur_sp = alloci(Msp + 1);
    int* idx_sp = alloci(NKsp);
    int* bsum   = alloci(4096);
    size_t avail_f = ws_size / 4;
    size_t remain = (avail_f > off4 + 16) ? (avail_f - off4 - 16) : 0;
    int CB = (int)(remain / (2 * (size_t)(Mbi + 1)));
    if (CB > NC) CB = NC;
    if (CB < 1) CB = 1;
    float* vbiA = allocf((size_t)(Mbi + 1) * CB);
    float* vbiB = allocf((size_t)(Mbi + 1) * CB);

    const int B = 256;
    const int nb_bi = cdiv_l(Mbi + 1, SCAN_CHUNK);
    const int nb_sp = cdiv_l(Msp + 1, SCAN_CHUNK);

    // ---- build CSR (row -> entry list), bilateral ----
    hipMemsetAsync(cur_bi, 0, (size_t)(Mbi + 1) * sizeof(int), stream);
    hist_k<<<cdiv_l(NKbi, B), B, 0, stream>>>(os_bi, cur_bi, NKbi);
    scan1_k<<<nb_bi, SCAN_T, 0, stream>>>(cur_bi, bsum, Mbi + 1);
    scan2_k<<<1, SCAN_T, 0, stream>>>(bsum, nb_bi, off_bi, Mbi + 1);
    scan3_k<<<nb_bi, SCAN_T, 0, stream>>>(cur_bi, bsum, off_bi, Mbi + 1);
    hipMemsetAsync(cur_bi, 0, (size_t)(Mbi + 1) * sizeof(int), stream);
    scatter_k<<<cdiv_l(NKbi, B), B, 0, stream>>>(os_bi, off_bi, cur_bi, idx_bi, NKbi);

    // ---- build CSR, spatial ----
    hipMemsetAsync(cur_sp, 0, (size_t)(Msp + 1) * sizeof(int), stream);
    hist_k<<<cdiv_l(NKsp, B), B, 0, stream>>>(os_sp, cur_sp, NKsp);
    scan1_k<<<nb_sp, SCAN_T, 0, stream>>>(cur_sp, bsum, Msp + 1);
    scan2_k<<<1, SCAN_T, 0, stream>>>(bsum, nb_sp, off_sp, Msp + 1);
    scan3_k<<<nb_sp, SCAN_T, 0, stream>>>(cur_sp, bsum, off_sp, Msp + 1);
    hipMemsetAsync(cur_sp, 0, (size_t)(Msp + 1) * sizeof(int), stream);
    scatter_k<<<cdiv_l(NKsp, B), B, 0, stream>>>(os_sp, off_sp, cur_sp, idx_sp, NKsp);

    // ---- Q = softmax(-u) ----
    softmax_init_k<<<cdiv_l(N, B), B, 0, stream>>>(unary, Q, N);

    // ---- bilateral normalization (C=1) ----
    splat_gather1_k<<<cdiv_l(Mbi + 1, B), B, 0, stream>>>(ws_bi, off_bi, idx_bi, vbiA, Mbi);
    {
        float* s = vbiA; float* d = vbiB;
        for (int j = 0; j < Kbi; j++) {
            blur1_k<<<cdiv_l(Mbi + 1, B), B, 0, stream>>>(s, d, nbr_bi + (size_t)j * Mbi * 2, Mbi);
            float* t = s; s = d; d = t;
        }
        slice_norm_k<<<cdiv_l(N, B), B, 0, stream>>>(ws_bi, os_bi, s, nrm_bi, N, Kbi, alpha_bi);
    }

    // ---- spatial normalization (C=1) ----
    splat_gather1_k<<<cdiv_l(Msp + 1, B), B, 0, stream>>>(ws_sp, off_sp, idx_sp, vspA, Msp);
    {
        float* s = vspA; float* d = vspB;
        for (int j = 0; j < Ksp; j++) {
            blur1_k<<<cdiv_l(Msp + 1, B), B, 0, stream>>>(s, d, nbr_sp + (size_t)j * Msp * 2, Msp);
            float* t = s; s = d; d = t;
        }
        slice_norm_k<<<cdiv_l(N, B), B, 0, stream>>>(ws_sp, os_sp, s, nrm_sp, N, Ksp, alpha_sp);
    }

    // ---- mean-field iterations ----
    for (int it = 0; it < 5; it++) {
        // bilateral, channel-chunked
        for (int c0 = 0; c0 < NC; c0 += CB) {
            int cb = (NC - c0 < CB) ? (NC - c0) : CB;
            splat_gatherQ_k<<<cdiv_l(Mbi + 1, B), B, 0, stream>>>(Q, nrm_bi, ws_bi, off_bi,
                                                                  idx_bi, vbiA, Mbi, Kbi, c0, cb);
            float* s = vbiA; float* d = vbiB;
            for (int j = 0; j < Kbi; j++) {
                blurC_k<<<cdiv_l((long)(Mbi + 1) * cb, B), B, 0, stream>>>(
                    s, d, nbr_bi + (size_t)j * Mbi * 2, Mbi, cb);
                float* t = s; s = d; d = t;
            }
            sliceC_k<<<cdiv_l(N, B), B, 0, stream>>>(ws_bi, os_bi, s, nrm_bi, bi_out,
                                                     N, Kbi, c0, cb, alpha_bi);
        }
        // spatial, single chunk
        splat_gatherQ_k<<<cdiv_l(Msp + 1, B), B, 0, stream>>>(Q, nrm_sp, ws_sp, off_sp,
                                                              idx_sp, vspA, Msp, Ksp, 0, NC);
        {
            float* s = vspA; float* d = vspB;
            for (int j = 0; j < Ksp; j++) {
                blurC_k<<<cdiv_l((long)(Msp + 1) * NC, B), B, 0, stream>>>(
                    s, d, nbr_sp + (size_t)j * Msp * 2, Msp, NC);
                float* t = s; s = d; d = t;
            }
            sliceC_k<<<cdiv_l(N, B), B, 0, stream>>>(ws_sp, os_sp, s, nrm_sp, sp_out,
                                                     N, Ksp, 0, NC, alpha_sp);
        }
        update_k<<<cdiv_l(N, B), B, 0, stream>>>(unary, bi_out, sp_out, Q, N);
    }
}

// Round 3
// 1532.334 us; speedup vs baseline: 10.0394x; 3.1514x over previous
//
#include <hip/hip_runtime.h>
#include <hip/hip_fp16.h>

#define NPIX (512 * 512)
#define NC 21
#define CP 11            // half2 pairs per padded row (22 halves)
#define SCAN_CHUNK 2048
#define SCAN_T 256

static inline int cdiv_l(long a, int b) { return (int)((a + b - 1) / b); }

// ---------------- CSR build: histogram -> scan -> scatter ----------------
__global__ void hist_k(const int* __restrict__ os, int* __restrict__ count, int NK) {
    int t = blockIdx.x * blockDim.x + threadIdx.x;
    if (t < NK) atomicAdd(&count[os[t]], 1);
}

__global__ void scan1_k(const int* __restrict__ count, int* __restrict__ bsum, int L) {
    __shared__ int s[SCAN_T];
    int base = blockIdx.x * SCAN_CHUNK;
    int tsum = 0;
    for (int j = threadIdx.x; j < SCAN_CHUNK; j += SCAN_T) {
        int i = base + j;
        tsum += (i < L) ? count[i] : 0;
    }
    s[threadIdx.x] = tsum; __syncthreads();
    for (int o = SCAN_T / 2; o > 0; o >>= 1) {
        if (threadIdx.x < o) s[threadIdx.x] += s[threadIdx.x + o];
        __syncthreads();
    }
    if (threadIdx.x == 0) bsum[blockIdx.x] = s[0];
}

__global__ void scan2_k(int* __restrict__ bsum, int nb, int* __restrict__ off, int L) {
    __shared__ int s[SCAN_T];
    int tid = threadIdx.x;
    int per = (nb + SCAN_T - 1) / SCAN_T;
    int tsum = 0;
    for (int j = 0; j < per; j++) { int i = tid * per + j; if (i < nb) tsum += bsum[i]; }
    s[tid] = tsum; __syncthreads();
    for (int o = 1; o < SCAN_T; o <<= 1) {
        int v = (tid >= o) ? s[tid - o] : 0;
        __syncthreads();
        s[tid] += v;
        __syncthreads();
    }
    int excl = s[tid] - tsum;
    int total = s[SCAN_T - 1];
    int run = excl;
    for (int j = 0; j < per; j++) {
        int i = tid * per + j;
        if (i < nb) { int v = bsum[i]; bsum[i] = run; run += v; }
    }
    if (tid == 0) off[L] = total;
}

__global__ void scan3_k(const int* __restrict__ count, const int* __restrict__ bsum,
                        int* __restrict__ off, int L) {
    __shared__ int s[SCAN_T];
    const int PER = SCAN_CHUNK / SCAN_T;  // 8
    int tid = threadIdx.x;
    int base = blockIdx.x * SCAN_CHUNK + tid * PER;
    int c[PER];
    int tsum = 0;
#pragma unroll
    for (int j = 0; j < PER; j++) { int i = base + j; c[j] = (i < L) ? count[i] : 0; tsum += c[j]; }
    s[tid] = tsum; __syncthreads();
    for (int o = 1; o < SCAN_T; o <<= 1) {
        int v = (tid >= o) ? s[tid - o] : 0;
        __syncthreads();
        s[tid] += v;
        __syncthreads();
    }
    int run = bsum[blockIdx.x] + s[tid] - tsum;
#pragma unroll
    for (int j = 0; j < PER; j++) {
        int i = base + j;
        if (i < L) off[i] = run;
        run += c[j];
    }
}

// scatter entry -> (pixel index, weight), grouped by lattice row
__global__ void scatter_k(const int* __restrict__ os, const float* __restrict__ ws,
                          const int* __restrict__ off, int* __restrict__ cur,
                          int* __restrict__ n_e, float* __restrict__ w_e, int NK, int K) {
    int t = blockIdx.x * blockDim.x + threadIdx.x;
    if (t >= NK) return;
    int m = os[t];
    int p = off[m] + atomicAdd(&cur[m], 1);
    n_e[p] = t / K;
    w_e[p] = ws[t];
}

// wn[e] *= nrm[n_e[e]]  (fold normalization into entry weight, once per call)
__global__ void wn_mul_k(float* __restrict__ w_e, const int* __restrict__ n_e,
                         const float* __restrict__ nrm, int NK) {
    int e = blockIdx.x * blockDim.x + threadIdx.x;
    if (e < NK) w_e[e] *= nrm[n_e[e]];
}

// ---------------- normalization lattice (C=1, f32) ----------------
__global__ void splat_gather1_k(const float* __restrict__ w_e, const int* __restrict__ off,
                                float* __restrict__ val, int M) {
    int m = blockIdx.x * blockDim.x + threadIdx.x;
    if (m > M) return;
    float s = 0.f;
    if (m > 0) {
        int e0 = off[m], e1 = off[m + 1];
        for (int e = e0; e < e1; e++) s += w_e[e];
    }
    val[m] = s;
}

__global__ void blur1_k(const float* __restrict__ vin, float* __restrict__ vout,
                        const int* __restrict__ nbr, int M) {
    int t = blockIdx.x * blockDim.x + threadIdx.x;
    if (t > M) return;
    if (t == 0) { vout[0] = 0.f; return; }
    int2 nn = ((const int2*)nbr)[t - 1];
    vout[t] = vin[t] + 0.5f * (vin[nn.x] + vin[nn.y]);
}

__global__ void slice_norm_k(const float* __restrict__ ws, const int* __restrict__ os,
                             const float* __restrict__ val, float* __restrict__ nrm,
                             int N, int K, float alpha) {
    int n = blockIdx.x * blockDim.x + threadIdx.x;
    if (n >= N) return;
    float s = 0.f;
    for (int j = 0; j < K; j++) s += ws[(size_t)n * K + j] * val[os[(size_t)n * K + j]];
    nrm[n] = 1.f / (sqrtf(alpha * s) + 1e-20f);
}

// ---------------- f16 lattice pipeline ----------------
// splat: one thread per lattice row; gathers padded f16 Q rows, writes padded f16 row
__global__ void splatH_k(const __half2* __restrict__ Qh, const int* __restrict__ n_e,
                         const float* __restrict__ wn, const int* __restrict__ off,
                         __half2* __restrict__ val, int M) {
    int m = blockIdx.x * blockDim.x + threadIdx.x;
    if (m > M) return;
    float acc[2 * CP];
#pragma unroll
    for (int i = 0; i < 2 * CP; i++) acc[i] = 0.f;
    if (m > 0) {
        int e0 = off[m], e1 = off[m + 1];
        for (int e = e0; e < e1; e++) {
            int n = n_e[e];
            float w = wn[e];
            const __half2* qp = Qh + (size_t)n * CP;
#pragma unroll
            for (int i = 0; i < CP; i++) {
                float2 q = __half22float2(qp[i]);
                acc[2 * i]     += w * q.x;
                acc[2 * i + 1] += w * q.y;
            }
        }
    }
    __half2* vp = val + (size_t)m * CP;
#pragma unroll
    for (int i = 0; i < CP; i++)
        vp[i] = __floats2half2_rn(acc[2 * i], acc[2 * i + 1]);
}

// blur: thread per (row, half2-pair)
__global__ void blurH_k(const __half2* __restrict__ vin, __half2* __restrict__ vout,
                        const int* __restrict__ nbr, int M) {
    int t = blockIdx.x * blockDim.x + threadIdx.x;
    int total = (M + 1) * CP;
    if (t >= total) return;
    int m = t / CP;
    int cp = t - m * CP;
    if (m == 0) { vout[t] = __floats2half2_rn(0.f, 0.f); return; }
    int2 nn = ((const int2*)nbr)[m - 1];
    float2 a = __half22float2(vin[t]);
    float2 b = __half22float2(vin[(size_t)nn.x * CP + cp]);
    float2 c = __half22float2(vin[(size_t)nn.y * CP + cp]);
    vout[t] = __floats2half2_rn(a.x + 0.5f * (b.x + c.x), a.y + 0.5f * (b.y + c.y));
}

// ---------------- softmax kernels ----------------
__global__ void softmax_init_k(const float* __restrict__ u, float* __restrict__ Q,
                               __half2* __restrict__ Qh, int N) {
    int n = blockIdx.x * blockDim.x + threadIdx.x;
    if (n >= N) return;
    const float* up = u + (size_t)n * NC;
    float v[2 * CP];
    float mx = -1e30f;
#pragma unroll
    for (int c = 0; c < NC; c++) { v[c] = -up[c]; mx = fmaxf(mx, v[c]); }
    float s = 0.f;
#pragma unroll
    for (int c = 0; c < NC; c++) { v[c] = __expf(v[c] - mx); s += v[c]; }
    float inv = 1.f / s;
#pragma unroll
    for (int c = 0; c < NC; c++) v[c] *= inv;
    v[NC] = 0.f;
    float* qp = Q + (size_t)n * NC;
#pragma unroll
    for (int c = 0; c < NC; c++) qp[c] = v[c];
    __half2* hp = Qh + (size_t)n * CP;
#pragma unroll
    for (int i = 0; i < CP; i++) hp[i] = __floats2half2_rn(v[2 * i], v[2 * i + 1]);
}

// fused: slice bilateral + slice spatial + softmax update -> Q (f32) and Qh (f16)
__global__ void slice_update_k(const float* __restrict__ u,
                               const int* __restrict__ os_bi, const float* __restrict__ ws_bi,
                               const __half2* __restrict__ vbi, const float* __restrict__ nrm_bi,
                               const int* __restrict__ os_sp, const float* __restrict__ ws_sp,
                               const __half2* __restrict__ vsp, const float* __restrict__ nrm_sp,
                               float* __restrict__ Q, __half2* __restrict__ Qh,
                               int N, float abi, float asp) {
    int n = blockIdx.x * blockDim.x + threadIdx.x;
    if (n >= N) return;
    float acc[2 * CP];
#pragma unroll
    for (int i = 0; i < 2 * CP; i++) acc[i] = 0.f;
    // bilateral slice
    for (int j = 0; j < 6; j++) {
        float w = ws_bi[(size_t)n * 6 + j];
        const __half2* vp = vbi + (size_t)os_bi[(size_t)n * 6 + j] * CP;
#pragma unroll
        for (int i = 0; i < CP; i++) {
            float2 f = __half22float2(vp[i]);
            acc[2 * i]     += w * f.x;
            acc[2 * i + 1] += w * f.y;
        }
    }
    float sb = 10.f * abi * nrm_bi[n];
#pragma unroll
    for (int i = 0; i < 2 * CP; i++) acc[i] *= sb;
    // spatial slice added in
    float ss = 3.f * asp * nrm_sp[n];
    for (int j = 0; j < 3; j++) {
        float w = ss * ws_sp[(size_t)n * 3 + j];
        const __half2* vp = vsp + (size_t)os_sp[(size_t)n * 3 + j] * CP;
#pragma unroll
        for (int i = 0; i < CP; i++) {
            float2 f = __half22float2(vp[i]);
            acc[2 * i]     += w * f.x;
            acc[2 * i + 1] += w * f.y;
        }
    }
    // logits = -u + acc ; softmax
    size_t base = (size_t)n * NC;
    float mx = -1e30f;
#pragma unroll
    for (int c = 0; c < NC; c++) { acc[c] -= u[base + c]; mx = fmaxf(mx, acc[c]); }
    float s = 0.f;
#pragma unroll
    for (int c = 0; c < NC; c++) { acc[c] = __expf(acc[c] - mx); s += acc[c]; }
    float inv = 1.f / s;
#pragma unroll
    for (int c = 0; c < NC; c++) acc[c] *= inv;
    acc[NC] = 0.f;
    float* qp = Q + base;
#pragma unroll
    for (int c = 0; c < NC; c++) qp[c] = acc[c];
    __half2* hp = Qh + (size_t)n * CP;
#pragma unroll
    for (int i = 0; i < CP; i++) hp[i] = __floats2half2_rn(acc[2 * i], acc[2 * i + 1]);
}

extern "C" void kernel_launch(void* const* d_in, const int* in_sizes, int n_in,
                              void* d_out, int out_size, void* d_ws, size_t ws_size,
                              hipStream_t stream) {
    const float* unary  = (const float*)d_in[0];
    const float* ws_bi  = (const float*)d_in[1];
    const float* ws_sp  = (const float*)d_in[2];
    const int*   os_bi  = (const int*)d_in[3];
    const int*   os_sp  = (const int*)d_in[4];
    const int*   nbr_bi = (const int*)d_in[5];
    const int*   nbr_sp = (const int*)d_in[6];
    float* Q = (float*)d_out;

    const int N = NPIX, Kbi = 6, Ksp = 3;
    const int Mbi = in_sizes[5] / (Kbi * 2);
    const int Msp = in_sizes[6] / (Ksp * 2);
    const int NKbi = N * Kbi, NKsp = N * Ksp;
    const float alpha_bi = 32.f / 33.f;
    const float alpha_sp = 0.8f;

    // ---- workspace layout (4-byte units) ----
    char* basec = (char*)d_ws;
    size_t off4 = 0;
    auto allocf = [&](size_t nf) { float* p = (float*)basec + off4; off4 += (nf + 3) & ~(size_t)3; return p; };
    auto alloci = [&](size_t ni) { int* p = (int*)basec + off4; off4 += (ni + 3) & ~(size_t)3; return p; };
    auto alloch2 = [&](size_t nh2) { __half2* p = (__half2*)((float*)basec + off4); off4 += (nh2 + 3) & ~(size_t)3; return p; };

    float*   nrm_bi = allocf(N);
    float*   nrm_sp = allocf(N);
    __half2* Qh     = alloch2((size_t)N * CP);
    int*     nE_bi  = alloci(NKbi);
    float*   wE_bi  = allocf(NKbi);
    int*     off_bi = alloci(Mbi + 2);
    int*     cur_bi = alloci(Mbi + 1);
    int*     nE_sp  = alloci(NKsp);
    float*   wE_sp  = allocf(NKsp);
    int*     off_sp = alloci(Msp + 2);
    int*     cur_sp = alloci(Msp + 1);
    int*     bsum   = alloci(4096);
    float*   nvA    = allocf(Mbi + 1);   // f32 norm-lattice buffers (reused for spatial)
    float*   nvB    = allocf(Mbi + 1);
    __half2* vbiA   = alloch2((size_t)(Mbi + 1) * CP);
    __half2* vbiB   = alloch2((size_t)(Mbi + 1) * CP);
    __half2* vspA   = alloch2((size_t)(Msp + 1) * CP);
    __half2* vspB   = alloch2((size_t)(Msp + 1) * CP);

    const int B = 256;
    const int nb_bi = cdiv_l(Mbi + 1, SCAN_CHUNK);
    const int nb_sp = cdiv_l(Msp + 1, SCAN_CHUNK);

    // ---- CSR build, bilateral ----
    hipMemsetAsync(cur_bi, 0, (size_t)(Mbi + 1) * sizeof(int), stream);
    hist_k<<<cdiv_l(NKbi, B), B, 0, stream>>>(os_bi, cur_bi, NKbi);
    scan1_k<<<nb_bi, SCAN_T, 0, stream>>>(cur_bi, bsum, Mbi + 1);
    scan2_k<<<1, SCAN_T, 0, stream>>>(bsum, nb_bi, off_bi, Mbi + 1);
    scan3_k<<<nb_bi, SCAN_T, 0, stream>>>(cur_bi, bsum, off_bi, Mbi + 1);
    hipMemsetAsync(cur_bi, 0, (size_t)(Mbi + 1) * sizeof(int), stream);
    scatter_k<<<cdiv_l(NKbi, B), B, 0, stream>>>(os_bi, ws_bi, off_bi, cur_bi, nE_bi, wE_bi, NKbi, Kbi);

    // ---- CSR build, spatial ----
    hipMemsetAsync(cur_sp, 0, (size_t)(Msp + 1) * sizeof(int), stream);
    hist_k<<<cdiv_l(NKsp, B), B, 0, stream>>>(os_sp, cur_sp, NKsp);
    scan1_k<<<nb_sp, SCAN_T, 0, stream>>>(cur_sp, bsum, Msp + 1);
    scan2_k<<<1, SCAN_T, 0, stream>>>(bsum, nb_sp, off_sp, Msp + 1);
    scan3_k<<<nb_sp, SCAN_T, 0, stream>>>(cur_sp, bsum, off_sp, Msp + 1);
    hipMemsetAsync(cur_sp, 0, (size_t)(Msp + 1) * sizeof(int), stream);
    scatter_k<<<cdiv_l(NKsp, B), B, 0, stream>>>(os_sp, ws_sp, off_sp, cur_sp, nE_sp, wE_sp, NKsp, Ksp);

    // ---- bilateral normalization (C=1, f32) ----
    splat_gather1_k<<<cdiv_l(Mbi + 1, B), B, 0, stream>>>(wE_bi, off_bi, nvA, Mbi);
    {
        float* s = nvA; float* d = nvB;
        for (int j = 0; j < Kbi; j++) {
            blur1_k<<<cdiv_l(Mbi + 1, B), B, 0, stream>>>(s, d, nbr_bi + (size_t)j * Mbi * 2, Mbi);
            float* t = s; s = d; d = t;
        }
        slice_norm_k<<<cdiv_l(N, B), B, 0, stream>>>(ws_bi, os_bi, s, nrm_bi, N, Kbi, alpha_bi);
    }

    // ---- spatial normalization (C=1, f32; reuse nvA/nvB) ----
    splat_gather1_k<<<cdiv_l(Msp + 1, B), B, 0, stream>>>(wE_sp, off_sp, nvA, Msp);
    {
        float* s = nvA; float* d = nvB;
        for (int j = 0; j < Ksp; j++) {
            blur1_k<<<cdiv_l(Msp + 1, B), B, 0, stream>>>(s, d, nbr_sp + (size_t)j * Msp * 2, Msp);
            float* t = s; s = d; d = t;
        }
        slice_norm_k<<<cdiv_l(N, B), B, 0, stream>>>(ws_sp, os_sp, s, nrm_sp, N, Ksp, alpha_sp);
    }

    // ---- fold nrm into entry weights ----
    wn_mul_k<<<cdiv_l(NKbi, B), B, 0, stream>>>(wE_bi, nE_bi, nrm_bi, NKbi);
    wn_mul_k<<<cdiv_l(NKsp, B), B, 0, stream>>>(wE_sp, nE_sp, nrm_sp, NKsp);

    // ---- Q = softmax(-u), plus f16 copy ----
    softmax_init_k<<<cdiv_l(N, B), B, 0, stream>>>(unary, Q, Qh, N);

    // ---- mean-field iterations ----
    for (int it = 0; it < 5; it++) {
        // bilateral lattice: splat + 6 blurs (ends in vbiA)
        splatH_k<<<cdiv_l(Mbi + 1, B), B, 0, stream>>>(Qh, nE_bi, wE_bi, off_bi, vbiA, Mbi);
        {
            __half2* s = vbiA; __half2* d = vbiB;
            for (int j = 0; j < Kbi; j++) {
                blurH_k<<<cdiv_l((long)(Mbi + 1) * CP, B), B, 0, stream>>>(
                    s, d, nbr_bi + (size_t)j * Mbi * 2, Mbi);
                __half2* t = s; s = d; d = t;
            }
        }
        // spatial lattice: splat + 3 blurs (ends in vspB)
        splatH_k<<<cdiv_l(Msp + 1, B), B, 0, stream>>>(Qh, nE_sp, wE_sp, off_sp, vspA, Msp);
        {
            __half2* s = vspA; __half2* d = vspB;
            for (int j = 0; j < Ksp; j++) {
                blurH_k<<<cdiv_l((long)(Msp + 1) * CP, B), B, 0, stream>>>(
                    s, d, nbr_sp + (size_t)j * Msp * 2, Msp);
                __half2* t = s; s = d; d = t;
            }
        }
        // fused slice + slice + softmax update
        slice_update_k<<<cdiv_l(N, B), B, 0, stream>>>(
            unary, os_bi, ws_bi, vbiA, nrm_bi, os_sp, ws_sp, vspB, nrm_sp,
            Q, Qh, N, alpha_bi, alpha_sp);
    }
}

// Round 4
// 1435.225 us; speedup vs baseline: 10.7187x; 1.0677x over previous
//
#include <hip/hip_runtime.h>
#include <hip/hip_fp16.h>

#define NPIX (512 * 512)
#define NC 21
#define CP 11            // half2 pairs per padded row (22 halves, 44 B)
#define SCAN_CHUNK 2048
#define SCAN_T 256

static inline int cdiv_l(long a, int b) { return (int)((a + b - 1) / b); }

// ---------------- CSR build: histogram -> scan -> scatter ----------------
// dual-range histogram (bilateral entries then spatial entries)
__global__ void hist2_k(const int* __restrict__ osA, int* __restrict__ cntA, int NA,
                        const int* __restrict__ osB, int* __restrict__ cntB, int NB) {
    int t = blockIdx.x * blockDim.x + threadIdx.x;
    if (t < NA) {
        atomicAdd(&cntA[osA[t]], 1);
    } else {
        t -= NA;
        if (t < NB) atomicAdd(&cntB[osB[t]], 1);
    }
}

__global__ void scan1_k(const int* __restrict__ count, int* __restrict__ bsum, int L) {
    __shared__ int s[SCAN_T];
    int base = blockIdx.x * SCAN_CHUNK;
    int tsum = 0;
    for (int j = threadIdx.x; j < SCAN_CHUNK; j += SCAN_T) {
        int i = base + j;
        tsum += (i < L) ? count[i] : 0;
    }
    s[threadIdx.x] = tsum; __syncthreads();
    for (int o = SCAN_T / 2; o > 0; o >>= 1) {
        if (threadIdx.x < o) s[threadIdx.x] += s[threadIdx.x + o];
        __syncthreads();
    }
    if (threadIdx.x == 0) bsum[blockIdx.x] = s[0];
}

__global__ void scan2_k(int* __restrict__ bsum, int nb, int* __restrict__ off, int L) {
    __shared__ int s[SCAN_T];
    int tid = threadIdx.x;
    int per = (nb + SCAN_T - 1) / SCAN_T;
    int tsum = 0;
    for (int j = 0; j < per; j++) { int i = tid * per + j; if (i < nb) tsum += bsum[i]; }
    s[tid] = tsum; __syncthreads();
    for (int o = 1; o < SCAN_T; o <<= 1) {
        int v = (tid >= o) ? s[tid - o] : 0;
        __syncthreads();
        s[tid] += v;
        __syncthreads();
    }
    int excl = s[tid] - tsum;
    int total = s[SCAN_T - 1];
    int run = excl;
    for (int j = 0; j < per; j++) {
        int i = tid * per + j;
        if (i < nb) { int v = bsum[i]; bsum[i] = run; run += v; }
    }
    if (tid == 0) off[L] = total;
}

__global__ void scan3_k(const int* __restrict__ count, const int* __restrict__ bsum,
                        int* __restrict__ off, int L) {
    __shared__ int s[SCAN_T];
    const int PER = SCAN_CHUNK / SCAN_T;  // 8
    int tid = threadIdx.x;
    int base = blockIdx.x * SCAN_CHUNK + tid * PER;
    int c[PER];
    int tsum = 0;
#pragma unroll
    for (int j = 0; j < PER; j++) { int i = base + j; c[j] = (i < L) ? count[i] : 0; tsum += c[j]; }
    s[tid] = tsum; __syncthreads();
    for (int o = 1; o < SCAN_T; o <<= 1) {
        int v = (tid >= o) ? s[tid - o] : 0;
        __syncthreads();
        s[tid] += v;
        __syncthreads();
    }
    int run = bsum[blockIdx.x] + s[tid] - tsum;
#pragma unroll
    for (int j = 0; j < PER; j++) {
        int i = base + j;
        if (i < L) off[i] = run;
        run += c[j];
    }
}

// dual-range scatter: one packed 8B store per entry (pixel index, weight-bits)
__global__ void scatter2_k(const int* __restrict__ osA, const float* __restrict__ wsA,
                           const int* __restrict__ offA, int* __restrict__ curA,
                           int2* __restrict__ pA, int NA, int KA,
                           const int* __restrict__ osB, const float* __restrict__ wsB,
                           const int* __restrict__ offB, int* __restrict__ curB,
                           int2* __restrict__ pB, int NB, int KB) {
    int t = blockIdx.x * blockDim.x + threadIdx.x;
    if (t < NA) {
        int m = osA[t];
        int p = offA[m] + atomicAdd(&curA[m], 1);
        pA[p] = make_int2(t / KA, __float_as_int(wsA[t]));
    } else {
        t -= NA;
        if (t < NB) {
            int m = osB[t];
            int p = offB[m] + atomicAdd(&curB[m], 1);
            pB[p] = make_int2(t / KB, __float_as_int(wsB[t]));
        }
    }
}

// dual-range fold of nrm into packed entry weights (once per call)
__global__ void wn2_k(int2* __restrict__ pA, const float* __restrict__ nrmA, int NA,
                      int2* __restrict__ pB, const float* __restrict__ nrmB, int NB) {
    int t = blockIdx.x * blockDim.x + threadIdx.x;
    if (t < NA) {
        int2 e = pA[t];
        e.y = __float_as_int(__int_as_float(e.y) * nrmA[e.x]);
        pA[t] = e;
    } else {
        t -= NA;
        if (t < NB) {
            int2 e = pB[t];
            e.y = __float_as_int(__int_as_float(e.y) * nrmB[e.x]);
            pB[t] = e;
        }
    }
}

// ---------------- normalization lattice (C=1, f32) ----------------
__global__ void splat_gather1_k(const int2* __restrict__ pE, const int* __restrict__ off,
                                float* __restrict__ val, int M) {
    int m = blockIdx.x * blockDim.x + threadIdx.x;
    if (m > M) return;
    float s = 0.f;
    if (m > 0) {
        int e0 = off[m], e1 = off[m + 1];
        for (int e = e0; e < e1; e++) s += __int_as_float(pE[e].y);
    }
    val[m] = s;
}

__global__ void blur1_k(const float* __restrict__ vin, float* __restrict__ vout,
                        const int* __restrict__ nbr, int M) {
    int t = blockIdx.x * blockDim.x + threadIdx.x;
    if (t > M) return;
    if (t == 0) { vout[0] = 0.f; return; }
    int2 nn = ((const int2*)nbr)[t - 1];
    vout[t] = vin[t] + 0.5f * (vin[nn.x] + vin[nn.y]);
}

__global__ void slice_norm_k(const float* __restrict__ ws, const int* __restrict__ os,
                             const float* __restrict__ val, float* __restrict__ nrm,
                             int N, int K, float alpha) {
    int n = blockIdx.x * blockDim.x + threadIdx.x;
    if (n >= N) return;
    float s = 0.f;
    for (int j = 0; j < K; j++) s += ws[(size_t)n * K + j] * val[os[(size_t)n * K + j]];
    nrm[n] = 1.f / (sqrtf(alpha * s) + 1e-20f);
}

// ---------------- f16 lattice pipeline ----------------
__global__ void splatH_k(const __half2* __restrict__ Qh, const int2* __restrict__ pE,
                         const int* __restrict__ off, __half2* __restrict__ val, int M) {
    int m = blockIdx.x * blockDim.x + threadIdx.x;
    if (m > M) return;
    float acc[2 * CP];
#pragma unroll
    for (int i = 0; i < 2 * CP; i++) acc[i] = 0.f;
    if (m > 0) {
        int e0 = off[m], e1 = off[m + 1];
        for (int e = e0; e < e1; e++) {
            int2 ent = pE[e];
            float w = __int_as_float(ent.y);
            const __half2* qp = Qh + (size_t)ent.x * CP;
#pragma unroll
            for (int i = 0; i < CP; i++) {
                float2 q = __half22float2(qp[i]);
                acc[2 * i]     += w * q.x;
                acc[2 * i + 1] += w * q.y;
            }
        }
    }
    __half2* vp = val + (size_t)m * CP;
#pragma unroll
    for (int i = 0; i < CP; i++)
        vp[i] = __floats2half2_rn(acc[2 * i], acc[2 * i + 1]);
}

__global__ void blurH_k(const __half2* __restrict__ vin, __half2* __restrict__ vout,
                        const int* __restrict__ nbr, int M) {
    int t = blockIdx.x * blockDim.x + threadIdx.x;
    int total = (M + 1) * CP;
    if (t >= total) return;
    int m = t / CP;
    int cp = t - m * CP;
    if (m == 0) { vout[t] = __floats2half2_rn(0.f, 0.f); return; }
    int2 nn = ((const int2*)nbr)[m - 1];
    float2 a = __half22float2(vin[t]);
    float2 b = __half22float2(vin[(size_t)nn.x * CP + cp]);
    float2 c = __half22float2(vin[(size_t)nn.y * CP + cp]);
    vout[t] = __floats2half2_rn(a.x + 0.5f * (b.x + c.x), a.y + 0.5f * (b.y + c.y));
}

// ---------------- softmax kernels ----------------
// Qh = softmax(-u) in f16 (padded); uh = u in f16 (padded). No f32 Q write.
__global__ void softmax_init_k(const float* __restrict__ u, __half2* __restrict__ Qh,
                               __half2* __restrict__ uh, int N) {
    int n = blockIdx.x * blockDim.x + threadIdx.x;
    if (n >= N) return;
    const float* up = u + (size_t)n * NC;
    float uv[2 * CP], v[2 * CP];
    float mx = -1e30f;
#pragma unroll
    for (int c = 0; c < NC; c++) { uv[c] = up[c]; v[c] = -uv[c]; mx = fmaxf(mx, v[c]); }
    float s = 0.f;
#pragma unroll
    for (int c = 0; c < NC; c++) { v[c] = __expf(v[c] - mx); s += v[c]; }
    float inv = 1.f / s;
#pragma unroll
    for (int c = 0; c < NC; c++) v[c] *= inv;
    v[NC] = 0.f; uv[NC] = 0.f;
    __half2* hp = Qh + (size_t)n * CP;
    __half2* uhp = uh + (size_t)n * CP;
#pragma unroll
    for (int i = 0; i < CP; i++) {
        hp[i]  = __floats2half2_rn(v[2 * i], v[2 * i + 1]);
        uhp[i] = __floats2half2_rn(uv[2 * i], uv[2 * i + 1]);
    }
}

// fused: slice bilateral + slice spatial + softmax update.
// final==0: write Qh only. final==1: write f32 Q only.
__global__ void slice_update_k(const __half2* __restrict__ uh,
                               const int* __restrict__ os_bi, const float* __restrict__ ws_bi,
                               const __half2* __restrict__ vbi, const float* __restrict__ nrm_bi,
                               const int* __restrict__ os_sp, const float* __restrict__ ws_sp,
                               const __half2* __restrict__ vsp, const float* __restrict__ nrm_sp,
                               float* __restrict__ Q, __half2* __restrict__ Qh,
                               int N, float abi, float asp, int final_it) {
    int n = blockIdx.x * blockDim.x + threadIdx.x;
    if (n >= N) return;
    float acc[2 * CP];
#pragma unroll
    for (int i = 0; i < 2 * CP; i++) acc[i] = 0.f;
    // bilateral slice
    for (int j = 0; j < 6; j++) {
        float w = ws_bi[(size_t)n * 6 + j];
        const __half2* vp = vbi + (size_t)os_bi[(size_t)n * 6 + j] * CP;
#pragma unroll
        for (int i = 0; i < CP; i++) {
            float2 f = __half22float2(vp[i]);
            acc[2 * i]     += w * f.x;
            acc[2 * i + 1] += w * f.y;
        }
    }
    float sb = 10.f * abi * nrm_bi[n];
#pragma unroll
    for (int i = 0; i < 2 * CP; i++) acc[i] *= sb;
    // spatial slice added in
    float ss = 3.f * asp * nrm_sp[n];
    for (int j = 0; j < 3; j++) {
        float w = ss * ws_sp[(size_t)n * 3 + j];
        const __half2* vp = vsp + (size_t)os_sp[(size_t)n * 3 + j] * CP;
#pragma unroll
        for (int i = 0; i < CP; i++) {
            float2 f = __half22float2(vp[i]);
            acc[2 * i]     += w * f.x;
            acc[2 * i + 1] += w * f.y;
        }
    }
    // logits = -u + acc ; softmax over c < NC
    const __half2* uhp = uh + (size_t)n * CP;
#pragma unroll
    for (int i = 0; i < CP; i++) {
        float2 uu = __half22float2(uhp[i]);
        acc[2 * i]     -= uu.x;
        acc[2 * i + 1] -= uu.y;
    }
    float mx = -1e30f;
#pragma unroll
    for (int c = 0; c < NC; c++) mx = fmaxf(mx, acc[c]);
    float s = 0.f;
#pragma unroll
    for (int c = 0; c < NC; c++) { acc[c] = __expf(acc[c] - mx); s += acc[c]; }
    float inv = 1.f / s;
#pragma unroll
    for (int c = 0; c < NC; c++) acc[c] *= inv;
    acc[NC] = 0.f;
    if (final_it) {
        float* qp = Q + (size_t)n * NC;
#pragma unroll
        for (int c = 0; c < NC; c++) qp[c] = acc[c];
    } else {
        __half2* hp = Qh + (size_t)n * CP;
#pragma unroll
        for (int i = 0; i < CP; i++) hp[i] = __floats2half2_rn(acc[2 * i], acc[2 * i + 1]);
    }
}

extern "C" void kernel_launch(void* const* d_in, const int* in_sizes, int n_in,
                              void* d_out, int out_size, void* d_ws, size_t ws_size,
                              hipStream_t stream) {
    const float* unary  = (const float*)d_in[0];
    const float* ws_bi  = (const float*)d_in[1];
    const float* ws_sp  = (const float*)d_in[2];
    const int*   os_bi  = (const int*)d_in[3];
    const int*   os_sp  = (const int*)d_in[4];
    const int*   nbr_bi = (const int*)d_in[5];
    const int*   nbr_sp = (const int*)d_in[6];
    float* Q = (float*)d_out;

    const int N = NPIX, Kbi = 6, Ksp = 3;
    const int Mbi = in_sizes[5] / (Kbi * 2);
    const int Msp = in_sizes[6] / (Ksp * 2);
    const int NKbi = N * Kbi, NKsp = N * Ksp;
    const float alpha_bi = 32.f / 33.f;
    const float alpha_sp = 0.8f;

    // ---- workspace layout (4-byte units, 16B-aligned chunks) ----
    char* basec = (char*)d_ws;
    size_t off4 = 0;
    auto allocf = [&](size_t nf) { float* p = (float*)basec + off4; off4 += (nf + 3) & ~(size_t)3; return p; };
    auto alloci = [&](size_t ni) { int* p = (int*)basec + off4; off4 += (ni + 3) & ~(size_t)3; return p; };
    auto alloch2 = [&](size_t nh2) { __half2* p = (__half2*)((float*)basec + off4); off4 += (nh2 + 3) & ~(size_t)3; return p; };
    auto alloci2 = [&](size_t ni2) { int2* p = (int2*)((float*)basec + off4); off4 += 2 * ni2; return p; };

    float*   nrm_bi = allocf(N);
    float*   nrm_sp = allocf(N);
    __half2* Qh     = alloch2((size_t)N * CP);
    __half2* uh     = alloch2((size_t)N * CP);
    int2*    pE_bi  = alloci2(NKbi);
    int*     off_bi = alloci(Mbi + 2);
    int2*    pE_sp  = alloci2(NKsp);
    int*     off_sp = alloci(Msp + 2);
    int*     cur_bi = alloci((size_t)(Mbi + 1) + (Msp + 1));  // cur_sp adjacent
    int*     cur_sp = cur_bi + (Mbi + 1);
    int*     bsum   = alloci(4096);
    __half2* vbiA   = alloch2((size_t)(Mbi + 1) * CP);
    __half2* vbiB   = alloch2((size_t)(Mbi + 1) * CP);
    __half2* vspA   = alloch2((size_t)(Msp + 1) * CP);
    __half2* vspB   = alloch2((size_t)(Msp + 1) * CP);
    // f32 norm-lattice buffers reuse the (not-yet-live) f16 value regions
    float* nv_biA = (float*)vbiA;
    float* nv_biB = (float*)vbiB;
    float* nv_spA = (float*)vspA;
    float* nv_spB = (float*)vspB;

    const int B = 256;
    const int nb_bi = cdiv_l(Mbi + 1, SCAN_CHUNK);
    const int nb_sp = cdiv_l(Msp + 1, SCAN_CHUNK);
    const size_t cur_span = ((size_t)(Mbi + 1) + (Msp + 1)) * sizeof(int);

    // ---- CSR build (both lattices) ----
    hipMemsetAsync(cur_bi, 0, cur_span, stream);
    hist2_k<<<cdiv_l((long)NKbi + NKsp, B), B, 0, stream>>>(os_bi, cur_bi, NKbi, os_sp, cur_sp, NKsp);
    scan1_k<<<nb_bi, SCAN_T, 0, stream>>>(cur_bi, bsum, Mbi + 1);
    scan2_k<<<1, SCAN_T, 0, stream>>>(bsum, nb_bi, off_bi, Mbi + 1);
    scan3_k<<<nb_bi, SCAN_T, 0, stream>>>(cur_bi, bsum, off_bi, Mbi + 1);
    scan1_k<<<nb_sp, SCAN_T, 0, stream>>>(cur_sp, bsum, Msp + 1);
    scan2_k<<<1, SCAN_T, 0, stream>>>(bsum, nb_sp, off_sp, Msp + 1);
    scan3_k<<<nb_sp, SCAN_T, 0, stream>>>(cur_sp, bsum, off_sp, Msp + 1);
    hipMemsetAsync(cur_bi, 0, cur_span, stream);
    scatter2_k<<<cdiv_l((long)NKbi + NKsp, B), B, 0, stream>>>(
        os_bi, ws_bi, off_bi, cur_bi, pE_bi, NKbi, Kbi,
        os_sp, ws_sp, off_sp, cur_sp, pE_sp, NKsp, Ksp);

    // ---- bilateral normalization (C=1, f32; uses vbi regions) ----
    splat_gather1_k<<<cdiv_l(Mbi + 1, B), B, 0, stream>>>(pE_bi, off_bi, nv_biA, Mbi);
    {
        float* s = nv_biA; float* d = nv_biB;
        for (int j = 0; j < Kbi; j++) {
            blur1_k<<<cdiv_l(Mbi + 1, B), B, 0, stream>>>(s, d, nbr_bi + (size_t)j * Mbi * 2, Mbi);
            float* t = s; s = d; d = t;
        }
        slice_norm_k<<<cdiv_l(N, B), B, 0, stream>>>(ws_bi, os_bi, s, nrm_bi, N, Kbi, alpha_bi);
    }

    // ---- spatial normalization (C=1, f32; uses vsp regions) ----
    splat_gather1_k<<<cdiv_l(Msp + 1, B), B, 0, stream>>>(pE_sp, off_sp, nv_spA, Msp);
    {
        float* s = nv_spA; float* d = nv_spB;
        for (int j = 0; j < Ksp; j++) {
            blur1_k<<<cdiv_l(Msp + 1, B), B, 0, stream>>>(s, d, nbr_sp + (size_t)j * Msp * 2, Msp);
            float* t = s; s = d; d = t;
        }
        slice_norm_k<<<cdiv_l(N, B), B, 0, stream>>>(ws_sp, os_sp, s, nrm_sp, N, Ksp, alpha_sp);
    }

    // ---- fold nrm into packed entry weights ----
    wn2_k<<<cdiv_l((long)NKbi + NKsp, B), B, 0, stream>>>(pE_bi, nrm_bi, NKbi, pE_sp, nrm_sp, NKsp);

    // ---- Qh = softmax(-u) f16; uh = u f16 ----
    softmax_init_k<<<cdiv_l(N, B), B, 0, stream>>>(unary, Qh, uh, N);

    // ---- mean-field iterations ----
    for (int it = 0; it < 5; it++) {
        // bilateral lattice: splat + 6 blurs (ends in vbiA)
        splatH_k<<<cdiv_l(Mbi + 1, B), B, 0, stream>>>(Qh, pE_bi, off_bi, vbiA, Mbi);
        {
            __half2* s = vbiA; __half2* d = vbiB;
            for (int j = 0; j < Kbi; j++) {
                blurH_k<<<cdiv_l((long)(Mbi + 1) * CP, B), B, 0, stream>>>(
                    s, d, nbr_bi + (size_t)j * Mbi * 2, Mbi);
                __half2* t = s; s = d; d = t;
            }
        }
        // spatial lattice: splat + 3 blurs (ends in vspB)
        splatH_k<<<cdiv_l(Msp + 1, B), B, 0, stream>>>(Qh, pE_sp, off_sp, vspA, Msp);
        {
            __half2* s = vspA; __half2* d = vspB;
            for (int j = 0; j < Ksp; j++) {
                blurH_k<<<cdiv_l((long)(Msp + 1) * CP, B), B, 0, stream>>>(
                    s, d, nbr_sp + (size_t)j * Msp * 2, Msp);
                __half2* t = s; s = d; d = t;
            }
        }
        slice_update_k<<<cdiv_l(N, B), B, 0, stream>>>(
            uh, os_bi, ws_bi, vbiA, nrm_bi, os_sp, ws_sp, vspB, nrm_sp,
            Q, Qh, N, alpha_bi, alpha_sp, it == 4 ? 1 : 0);
    }
}

// Round 5
// 1268.789 us; speedup vs baseline: 12.1247x; 1.1312x over previous
//
#include <hip/hip_runtime.h>
#include <hip/hip_fp16.h>

#define NPIX (512 * 512)
#define NC 21
#define CP 11            // half2 pairs per padded row (22 halves, 44 B)
#define SCAN_CHUNK 2048
#define SCAN_T 256

static inline int cdiv_l(long a, int b) { return (int)((a + b - 1) / b); }

// ---------------- CSR build: histogram -> scan -> scatter ----------------
__global__ void hist2_k(const int* __restrict__ osA, int* __restrict__ cntA, int NA,
                        const int* __restrict__ osB, int* __restrict__ cntB, int NB) {
    int t = blockIdx.x * blockDim.x + threadIdx.x;
    if (t < NA) {
        atomicAdd(&cntA[osA[t]], 1);
    } else {
        t -= NA;
        if (t < NB) atomicAdd(&cntB[osB[t]], 1);
    }
}

__global__ void scan1_k(const int* __restrict__ count, int* __restrict__ bsum, int L) {
    __shared__ int s[SCAN_T];
    int base = blockIdx.x * SCAN_CHUNK;
    int tsum = 0;
    for (int j = threadIdx.x; j < SCAN_CHUNK; j += SCAN_T) {
        int i = base + j;
        tsum += (i < L) ? count[i] : 0;
    }
    s[threadIdx.x] = tsum; __syncthreads();
    for (int o = SCAN_T / 2; o > 0; o >>= 1) {
        if (threadIdx.x < o) s[threadIdx.x] += s[threadIdx.x + o];
        __syncthreads();
    }
    if (threadIdx.x == 0) bsum[blockIdx.x] = s[0];
}

__global__ void scan2_k(int* __restrict__ bsum, int nb, int* __restrict__ off, int L) {
    __shared__ int s[SCAN_T];
    int tid = threadIdx.x;
    int per = (nb + SCAN_T - 1) / SCAN_T;
    int tsum = 0;
    for (int j = 0; j < per; j++) { int i = tid * per + j; if (i < nb) tsum += bsum[i]; }
    s[tid] = tsum; __syncthreads();
    for (int o = 1; o < SCAN_T; o <<= 1) {
        int v = (tid >= o) ? s[tid - o] : 0;
        __syncthreads();
        s[tid] += v;
        __syncthreads();
    }
    int excl = s[tid] - tsum;
    int total = s[SCAN_T - 1];
    int run = excl;
    for (int j = 0; j < per; j++) {
        int i = tid * per + j;
        if (i < nb) { int v = bsum[i]; bsum[i] = run; run += v; }
    }
    if (tid == 0) off[L] = total;
}

// final exclusive scan; also zeroes count[] in place (replaces a memset dispatch)
__global__ void scan3_k(int* __restrict__ count, const int* __restrict__ bsum,
                        int* __restrict__ off, int L) {
    __shared__ int s[SCAN_T];
    const int PER = SCAN_CHUNK / SCAN_T;  // 8
    int tid = threadIdx.x;
    int base = blockIdx.x * SCAN_CHUNK + tid * PER;
    int c[PER];
    int tsum = 0;
#pragma unroll
    for (int j = 0; j < PER; j++) { int i = base + j; c[j] = (i < L) ? count[i] : 0; tsum += c[j]; }
    s[tid] = tsum; __syncthreads();
    for (int o = 1; o < SCAN_T; o <<= 1) {
        int v = (tid >= o) ? s[tid - o] : 0;
        __syncthreads();
        s[tid] += v;
        __syncthreads();
    }
    int run = bsum[blockIdx.x] + s[tid] - tsum;
#pragma unroll
    for (int j = 0; j < PER; j++) {
        int i = base + j;
        if (i < L) { off[i] = run; count[i] = 0; }
        run += c[j];
    }
}

// dual-range scatter: one packed 8B store per entry (pixel index, weight-bits)
__global__ void scatter2_k(const int* __restrict__ osA, const float* __restrict__ wsA,
                           const int* __restrict__ offA, int* __restrict__ curA,
                           int2* __restrict__ pA, int NA, int KA,
                           const int* __restrict__ osB, const float* __restrict__ wsB,
                           const int* __restrict__ offB, int* __restrict__ curB,
                           int2* __restrict__ pB, int NB, int KB) {
    int t = blockIdx.x * blockDim.x + threadIdx.x;
    if (t < NA) {
        int m = osA[t];
        int p = offA[m] + atomicAdd(&curA[m], 1);
        pA[p] = make_int2(t / KA, __float_as_int(wsA[t]));
    } else {
        t -= NA;
        if (t < NB) {
            int m = osB[t];
            int p = offB[m] + atomicAdd(&curB[m], 1);
            pB[p] = make_int2(t / KB, __float_as_int(wsB[t]));
        }
    }
}

// dual-range fold of nrm into packed entry weights (once per call)
__global__ void wn2_k(int2* __restrict__ pA, const float* __restrict__ nrmA, int NA,
                      int2* __restrict__ pB, const float* __restrict__ nrmB, int NB) {
    int t = blockIdx.x * blockDim.x + threadIdx.x;
    if (t < NA) {
        int2 e = pA[t];
        e.y = __float_as_int(__int_as_float(e.y) * nrmA[e.x]);
        pA[t] = e;
    } else {
        t -= NA;
        if (t < NB) {
            int2 e = pB[t];
            e.y = __float_as_int(__int_as_float(e.y) * nrmB[e.x]);
            pB[t] = e;
        }
    }
}

// ---------------- normalization lattice (C=1, f32) ----------------
__global__ void splat_gather1_k(const int2* __restrict__ pE, const int* __restrict__ off,
                                float* __restrict__ val, int M) {
    int m = blockIdx.x * blockDim.x + threadIdx.x;
    if (m > M) return;
    float s = 0.f;
    if (m > 0) {
        int e0 = off[m], e1 = off[m + 1];
        for (int e = e0; e < e1; e++) s += __int_as_float(pE[e].y);
    }
    val[m] = s;
}

__global__ void blur1_k(const float* __restrict__ vin, float* __restrict__ vout,
                        const int* __restrict__ nbr, int M) {
    int t = blockIdx.x * blockDim.x + threadIdx.x;
    if (t > M) return;
    if (t == 0) { vout[0] = 0.f; return; }
    int2 nn = ((const int2*)nbr)[t - 1];
    vout[t] = vin[t] + 0.5f * (vin[nn.x] + vin[nn.y]);
}

__global__ void slice_norm_k(const float* __restrict__ ws, const int* __restrict__ os,
                             const float* __restrict__ val, float* __restrict__ nrm,
                             int N, int K, float alpha) {
    int n = blockIdx.x * blockDim.x + threadIdx.x;
    if (n >= N) return;
    float s = 0.f;
    for (int j = 0; j < K; j++) s += ws[(size_t)n * K + j] * val[os[(size_t)n * K + j]];
    nrm[n] = 1.f / (sqrtf(alpha * s) + 1e-20f);
}

// ---------------- f16 lattice pipeline ----------------
__global__ void splatH_k(const __half2* __restrict__ Qh, const int2* __restrict__ pE,
                         const int* __restrict__ off, __half2* __restrict__ val, int M) {
    int m = blockIdx.x * blockDim.x + threadIdx.x;
    if (m > M) return;
    float acc[2 * CP];
#pragma unroll
    for (int i = 0; i < 2 * CP; i++) acc[i] = 0.f;
    if (m > 0) {
        int e0 = off[m], e1 = off[m + 1];
        for (int e = e0; e < e1; e++) {
            int2 ent = pE[e];
            float w = __int_as_float(ent.y);
            const __half2* qp = Qh + (size_t)ent.x * CP;
#pragma unroll
            for (int i = 0; i < CP; i++) {
                float2 q = __half22float2(qp[i]);
                acc[2 * i]     += w * q.x;
                acc[2 * i + 1] += w * q.y;
            }
        }
    }
    __half2* vp = val + (size_t)m * CP;
#pragma unroll
    for (int i = 0; i < CP; i++)
        vp[i] = __floats2half2_rn(acc[2 * i], acc[2 * i + 1]);
}

// single blur sweep: thread per (row, half2-pair)
__global__ void blurH_k(const __half2* __restrict__ vin, __half2* __restrict__ vout,
                        const int* __restrict__ nbr, int M) {
    int t = blockIdx.x * blockDim.x + threadIdx.x;
    int total = (M + 1) * CP;
    if (t >= total) return;
    int m = t / CP;
    int cp = t - m * CP;
    if (m == 0) { vout[t] = __floats2half2_rn(0.f, 0.f); return; }
    int2 nn = ((const int2*)nbr)[m - 1];
    float2 a = __half22float2(vin[t]);
    float2 b = __half22float2(vin[(size_t)nn.x * CP + cp]);
    float2 c = __half22float2(vin[(size_t)nn.y * CP + cp]);
    vout[t] = __floats2half2_rn(a.x + 0.5f * (b.x + c.x), a.y + 0.5f * (b.y + c.y));
}

// fused double blur: applies direction A then direction B in one pass.
// out[m] = bA[m] + 0.5*(bA[a1] + bA[a2]), a=nbrB[m]; bA[r] = vin[r]+0.5*(vin[nbrA[r].x]+vin[nbrA[r].y])
// thread per row; vin row 0 is all zeros so nbrA==0 gathers are harmless; bA[0]=0 handled by skip.
__global__ void blurH2_k(const __half2* __restrict__ vin, __half2* __restrict__ vout,
                         const int* __restrict__ nbrA, const int* __restrict__ nbrB, int M) {
    int m = blockIdx.x * blockDim.x + threadIdx.x;
    if (m > M) return;
    __half2* op = vout + (size_t)m * CP;
    if (m == 0) {
        __half2 z = __floats2half2_rn(0.f, 0.f);
#pragma unroll
        for (int i = 0; i < CP; i++) op[i] = z;
        return;
    }
    float acc[2 * CP];
#pragma unroll
    for (int i = 0; i < 2 * CP; i++) acc[i] = 0.f;
    int2 nbB = ((const int2*)nbrB)[m - 1];

    // contribution of bA[m] with weight 1
    {
        int2 na = ((const int2*)nbrA)[m - 1];
        const __half2* p0 = vin + (size_t)m * CP;
        const __half2* p1 = vin + (size_t)na.x * CP;
        const __half2* p2 = vin + (size_t)na.y * CP;
#pragma unroll
        for (int i = 0; i < CP; i++) {
            float2 a = __half22float2(p0[i]);
            float2 b = __half22float2(p1[i]);
            float2 c = __half22float2(p2[i]);
            acc[2 * i]     += a.x + 0.5f * (b.x + c.x);
            acc[2 * i + 1] += a.y + 0.5f * (b.y + c.y);
        }
    }
    // contribution of 0.5*bA[a1], 0.5*bA[a2]
    if (nbB.x > 0) {
        int2 na = ((const int2*)nbrA)[nbB.x - 1];
        const __half2* p0 = vin + (size_t)nbB.x * CP;
        const __half2* p1 = vin + (size_t)na.x * CP;
        const __half2* p2 = vin + (size_t)na.y * CP;
#pragma unroll
        for (int i = 0; i < CP; i++) {
            float2 a = __half22float2(p0[i]);
            float2 b = __half22float2(p1[i]);
            float2 c = __half22float2(p2[i]);
            acc[2 * i]     += 0.5f * (a.x + 0.5f * (b.x + c.x));
            acc[2 * i + 1] += 0.5f * (a.y + 0.5f * (b.y + c.y));
        }
    }
    if (nbB.y > 0) {
        int2 na = ((const int2*)nbrA)[nbB.y - 1];
        const __half2* p0 = vin + (size_t)nbB.y * CP;
        const __half2* p1 = vin + (size_t)na.x * CP;
        const __half2* p2 = vin + (size_t)na.y * CP;
#pragma unroll
        for (int i = 0; i < CP; i++) {
            float2 a = __half22float2(p0[i]);
            float2 b = __half22float2(p1[i]);
            float2 c = __half22float2(p2[i]);
            acc[2 * i]     += 0.5f * (a.x + 0.5f * (b.x + c.x));
            acc[2 * i + 1] += 0.5f * (a.y + 0.5f * (b.y + c.y));
        }
    }
#pragma unroll
    for (int i = 0; i < CP; i++)
        op[i] = __floats2half2_rn(acc[2 * i], acc[2 * i + 1]);
}

// ---------------- softmax kernels ----------------
__global__ void softmax_init_k(const float* __restrict__ u, __half2* __restrict__ Qh,
                               __half2* __restrict__ uh, int N) {
    int n = blockIdx.x * blockDim.x + threadIdx.x;
    if (n >= N) return;
    const float* up = u + (size_t)n * NC;
    float uv[2 * CP], v[2 * CP];
    float mx = -1e30f;
#pragma unroll
    for (int c = 0; c < NC; c++) { uv[c] = up[c]; v[c] = -uv[c]; mx = fmaxf(mx, v[c]); }
    float s = 0.f;
#pragma unroll
    for (int c = 0; c < NC; c++) { v[c] = __expf(v[c] - mx); s += v[c]; }
    float inv = 1.f / s;
#pragma unroll
    for (int c = 0; c < NC; c++) v[c] *= inv;
    v[NC] = 0.f; uv[NC] = 0.f;
    __half2* hp = Qh + (size_t)n * CP;
    __half2* uhp = uh + (size_t)n * CP;
#pragma unroll
    for (int i = 0; i < CP; i++) {
        hp[i]  = __floats2half2_rn(v[2 * i], v[2 * i + 1]);
        uhp[i] = __floats2half2_rn(uv[2 * i], uv[2 * i + 1]);
    }
}

// fused: slice bilateral + slice spatial + softmax update.
__global__ void slice_update_k(const __half2* __restrict__ uh,
                               const int* __restrict__ os_bi, const float* __restrict__ ws_bi,
                               const __half2* __restrict__ vbi, const float* __restrict__ nrm_bi,
                               const int* __restrict__ os_sp, const float* __restrict__ ws_sp,
                               const __half2* __restrict__ vsp, const float* __restrict__ nrm_sp,
                               float* __restrict__ Q, __half2* __restrict__ Qh,
                               int N, float abi, float asp, int final_it) {
    int n = blockIdx.x * blockDim.x + threadIdx.x;
    if (n >= N) return;
    float acc[2 * CP];
#pragma unroll
    for (int i = 0; i < 2 * CP; i++) acc[i] = 0.f;
    for (int j = 0; j < 6; j++) {
        float w = ws_bi[(size_t)n * 6 + j];
        const __half2* vp = vbi + (size_t)os_bi[(size_t)n * 6 + j] * CP;
#pragma unroll
        for (int i = 0; i < CP; i++) {
            float2 f = __half22float2(vp[i]);
            acc[2 * i]     += w * f.x;
            acc[2 * i + 1] += w * f.y;
        }
    }
    float sb = 10.f * abi * nrm_bi[n];
#pragma unroll
    for (int i = 0; i < 2 * CP; i++) acc[i] *= sb;
    float ss = 3.f * asp * nrm_sp[n];
    for (int j = 0; j < 3; j++) {
        float w = ss * ws_sp[(size_t)n * 3 + j];
        const __half2* vp = vsp + (size_t)os_sp[(size_t)n * 3 + j] * CP;
#pragma unroll
        for (int i = 0; i < CP; i++) {
            float2 f = __half22float2(vp[i]);
            acc[2 * i]     += w * f.x;
            acc[2 * i + 1] += w * f.y;
        }
    }
    const __half2* uhp = uh + (size_t)n * CP;
#pragma unroll
    for (int i = 0; i < CP; i++) {
        float2 uu = __half22float2(uhp[i]);
        acc[2 * i]     -= uu.x;
        acc[2 * i + 1] -= uu.y;
    }
    float mx = -1e30f;
#pragma unroll
    for (int c = 0; c < NC; c++) mx = fmaxf(mx, acc[c]);
    float s = 0.f;
#pragma unroll
    for (int c = 0; c < NC; c++) { acc[c] = __expf(acc[c] - mx); s += acc[c]; }
    float inv = 1.f / s;
#pragma unroll
    for (int c = 0; c < NC; c++) acc[c] *= inv;
    acc[NC] = 0.f;
    if (final_it) {
        float* qp = Q + (size_t)n * NC;
#pragma unroll
        for (int c = 0; c < NC; c++) qp[c] = acc[c];
    } else {
        __half2* hp = Qh + (size_t)n * CP;
#pragma unroll
        for (int i = 0; i < CP; i++) hp[i] = __floats2half2_rn(acc[2 * i], acc[2 * i + 1]);
    }
}

extern "C" void kernel_launch(void* const* d_in, const int* in_sizes, int n_in,
                              void* d_out, int out_size, void* d_ws, size_t ws_size,
                              hipStream_t stream) {
    const float* unary  = (const float*)d_in[0];
    const float* ws_bi  = (const float*)d_in[1];
    const float* ws_sp  = (const float*)d_in[2];
    const int*   os_bi  = (const int*)d_in[3];
    const int*   os_sp  = (const int*)d_in[4];
    const int*   nbr_bi = (const int*)d_in[5];
    const int*   nbr_sp = (const int*)d_in[6];
    float* Q = (float*)d_out;

    const int N = NPIX, Kbi = 6, Ksp = 3;
    const int Mbi = in_sizes[5] / (Kbi * 2);
    const int Msp = in_sizes[6] / (Ksp * 2);
    const int NKbi = N * Kbi, NKsp = N * Ksp;
    const float alpha_bi = 32.f / 33.f;
    const float alpha_sp = 0.8f;

    // ---- workspace layout (4-byte units) ----
    char* basec = (char*)d_ws;
    size_t off4 = 0;
    auto allocf = [&](size_t nf) { float* p = (float*)basec + off4; off4 += (nf + 3) & ~(size_t)3; return p; };
    auto alloci = [&](size_t ni) { int* p = (int*)basec + off4; off4 += (ni + 3) & ~(size_t)3; return p; };
    auto alloch2 = [&](size_t nh2) { __half2* p = (__half2*)((float*)basec + off4); off4 += (nh2 + 3) & ~(size_t)3; return p; };
    auto alloci2 = [&](size_t ni2) { int2* p = (int2*)((float*)basec + off4); off4 += 2 * ni2; return p; };

    float*   nrm_bi = allocf(N);
    float*   nrm_sp = allocf(N);
    __half2* Qh     = alloch2((size_t)N * CP);
    __half2* uh     = alloch2((size_t)N * CP);
    int2*    pE_bi  = alloci2(NKbi);
    int*     off_bi = alloci(Mbi + 2);
    int2*    pE_sp  = alloci2(NKsp);
    int*     off_sp = alloci(Msp + 2);
    int*     cur_bi = alloci((size_t)(Mbi + 1) + (Msp + 1));
    int*     cur_sp = cur_bi + (Mbi + 1);
    int*     bsum   = alloci(4096);
    __half2* vbiA   = alloch2((size_t)(Mbi + 1) * CP);
    __half2* vbiB   = alloch2((size_t)(Mbi + 1) * CP);
    __half2* vspA   = alloch2((size_t)(Msp + 1) * CP);
    __half2* vspB   = alloch2((size_t)(Msp + 1) * CP);
    float* nv_biA = (float*)vbiA;
    float* nv_biB = (float*)vbiB;
    float* nv_spA = (float*)vspA;
    float* nv_spB = (float*)vspB;

    const int B = 256;
    const int nb_bi = cdiv_l(Mbi + 1, SCAN_CHUNK);
    const int nb_sp = cdiv_l(Msp + 1, SCAN_CHUNK);
    const size_t cur_span = ((size_t)(Mbi + 1) + (Msp + 1)) * sizeof(int);

    // ---- CSR build (both lattices) ----
    hipMemsetAsync(cur_bi, 0, cur_span, stream);
    hist2_k<<<cdiv_l((long)NKbi + NKsp, B), B, 0, stream>>>(os_bi, cur_bi, NKbi, os_sp, cur_sp, NKsp);
    scan1_k<<<nb_bi, SCAN_T, 0, stream>>>(cur_bi, bsum, Mbi + 1);
    scan2_k<<<1, SCAN_T, 0, stream>>>(bsum, nb_bi, off_bi, Mbi + 1);
    scan3_k<<<nb_bi, SCAN_T, 0, stream>>>(cur_bi, bsum, off_bi, Mbi + 1);
    scan1_k<<<nb_sp, SCAN_T, 0, stream>>>(cur_sp, bsum, Msp + 1);
    scan2_k<<<1, SCAN_T, 0, stream>>>(bsum, nb_sp, off_sp, Msp + 1);
    scan3_k<<<nb_sp, SCAN_T, 0, stream>>>(cur_sp, bsum, off_sp, Msp + 1);
    scatter2_k<<<cdiv_l((long)NKbi + NKsp, B), B, 0, stream>>>(
        os_bi, ws_bi, off_bi, cur_bi, pE_bi, NKbi, Kbi,
        os_sp, ws_sp, off_sp, cur_sp, pE_sp, NKsp, Ksp);

    // ---- bilateral normalization (C=1, f32; uses vbi regions) ----
    splat_gather1_k<<<cdiv_l(Mbi + 1, B), B, 0, stream>>>(pE_bi, off_bi, nv_biA, Mbi);
    {
        float* s = nv_biA; float* d = nv_biB;
        for (int j = 0; j < Kbi; j++) {
            blur1_k<<<cdiv_l(Mbi + 1, B), B, 0, stream>>>(s, d, nbr_bi + (size_t)j * Mbi * 2, Mbi);
            float* t = s; s = d; d = t;
        }
        slice_norm_k<<<cdiv_l(N, B), B, 0, stream>>>(ws_bi, os_bi, s, nrm_bi, N, Kbi, alpha_bi);
    }

    // ---- spatial normalization (C=1, f32; uses vsp regions) ----
    splat_gather1_k<<<cdiv_l(Msp + 1, B), B, 0, stream>>>(pE_sp, off_sp, nv_spA, Msp);
    {
        float* s = nv_spA; float* d = nv_spB;
        for (int j = 0; j < Ksp; j++) {
            blur1_k<<<cdiv_l(Msp + 1, B), B, 0, stream>>>(s, d, nbr_sp + (size_t)j * Msp * 2, Msp);
            float* t = s; s = d; d = t;
        }
        slice_norm_k<<<cdiv_l(N, B), B, 0, stream>>>(ws_sp, os_sp, s, nrm_sp, N, Ksp, alpha_sp);
    }

    // ---- fold nrm into packed entry weights ----
    wn2_k<<<cdiv_l((long)NKbi + NKsp, B), B, 0, stream>>>(pE_bi, nrm_bi, NKbi, pE_sp, nrm_sp, NKsp);

    // ---- Qh = softmax(-u) f16; uh = u f16 ----
    softmax_init_k<<<cdiv_l(N, B), B, 0, stream>>>(unary, Qh, uh, N);

    // ---- mean-field iterations ----
    for (int it = 0; it < 5; it++) {
        // bilateral lattice: splat into vbiA, then 3 fused double-blurs: A->B->A->B
        splatH_k<<<cdiv_l(Mbi + 1, B), B, 0, stream>>>(Qh, pE_bi, off_bi, vbiA, Mbi);
        blurH2_k<<<cdiv_l(Mbi + 1, B), B, 0, stream>>>(
            vbiA, vbiB, nbr_bi + (size_t)0 * Mbi * 2, nbr_bi + (size_t)1 * Mbi * 2, Mbi);
        blurH2_k<<<cdiv_l(Mbi + 1, B), B, 0, stream>>>(
            vbiB, vbiA, nbr_bi + (size_t)2 * Mbi * 2, nbr_bi + (size_t)3 * Mbi * 2, Mbi);
        blurH2_k<<<cdiv_l(Mbi + 1, B), B, 0, stream>>>(
            vbiA, vbiB, nbr_bi + (size_t)4 * Mbi * 2, nbr_bi + (size_t)5 * Mbi * 2, Mbi);
        // spatial lattice: splat into vspA, fused (0,1): A->B, single (2): B->A
        splatH_k<<<cdiv_l(Msp + 1, B), B, 0, stream>>>(Qh, pE_sp, off_sp, vspA, Msp);
        blurH2_k<<<cdiv_l(Msp + 1, B), B, 0, stream>>>(
            vspA, vspB, nbr_sp + (size_t)0 * Msp * 2, nbr_sp + (size_t)1 * Msp * 2, Msp);
        blurH_k<<<cdiv_l((long)(Msp + 1) * CP, B), B, 0, stream>>>(
            vspB, vspA, nbr_sp + (size_t)2 * Msp * 2, Msp);
        // fused slice + slice + softmax update (bilateral result in vbiB, spatial in vspA)
        slice_update_k<<<cdiv_l(N, B), B, 0, stream>>>(
            uh, os_bi, ws_bi, vbiB, nrm_bi, os_sp, ws_sp, vspA, nrm_sp,
            Q, Qh, N, alpha_bi, alpha_sp, it == 4 ? 1 : 0);
    }
}

// Round 6
// 1257.985 us; speedup vs baseline: 12.2289x; 1.0086x over previous
//
#include <hip/hip_runtime.h>
#include <hip/hip_fp16.h>

#define NPIX (512 * 512)
#define LOG2N 18         // NPIX == 2^18
#define NC 21
#define CP 11            // half2 pairs per padded row (22 halves, 44 B)
#define SCAN_CHUNK 2048
#define SCAN_T 256

static inline int cdiv_l(long a, int b) { return (int)((a + b - 1) / b); }

// ---------------- CSR build: histogram -> scan -> scatter ----------------
// j-major traversal: consecutive threads hit adjacent pixels within one
// simplex-vertex plane -> nearby (sorted) lattice rows -> sector-friendly
// atomics/stores. t' in [0, K*N): j = t' >> LOG2N, n = t' & (N-1), t = n*K+j.
__global__ void hist2_k(const int* __restrict__ osA, int* __restrict__ cntA, int NA, int KA,
                        const int* __restrict__ osB, int* __restrict__ cntB, int NB, int KB) {
    int t = blockIdx.x * blockDim.x + threadIdx.x;
    if (t < NA) {
        int j = t >> LOG2N, n = t & (NPIX - 1);
        atomicAdd(&cntA[osA[(size_t)n * KA + j]], 1);
    } else {
        t -= NA;
        if (t < NB) {
            int j = t >> LOG2N, n = t & (NPIX - 1);
            atomicAdd(&cntB[osB[(size_t)n * KB + j]], 1);
        }
    }
}

__global__ void scan1_k(const int* __restrict__ count, int* __restrict__ bsum, int L) {
    __shared__ int s[SCAN_T];
    int base = blockIdx.x * SCAN_CHUNK;
    int tsum = 0;
    for (int j = threadIdx.x; j < SCAN_CHUNK; j += SCAN_T) {
        int i = base + j;
        tsum += (i < L) ? count[i] : 0;
    }
    s[threadIdx.x] = tsum; __syncthreads();
    for (int o = SCAN_T / 2; o > 0; o >>= 1) {
        if (threadIdx.x < o) s[threadIdx.x] += s[threadIdx.x + o];
        __syncthreads();
    }
    if (threadIdx.x == 0) bsum[blockIdx.x] = s[0];
}

__global__ void scan2_k(int* __restrict__ bsum, int nb, int* __restrict__ off, int L) {
    __shared__ int s[SCAN_T];
    int tid = threadIdx.x;
    int per = (nb + SCAN_T - 1) / SCAN_T;
    int tsum = 0;
    for (int j = 0; j < per; j++) { int i = tid * per + j; if (i < nb) tsum += bsum[i]; }
    s[tid] = tsum; __syncthreads();
    for (int o = 1; o < SCAN_T; o <<= 1) {
        int v = (tid >= o) ? s[tid - o] : 0;
        __syncthreads();
        s[tid] += v;
        __syncthreads();
    }
    int excl = s[tid] - tsum;
    int total = s[SCAN_T - 1];
    int run = excl;
    for (int j = 0; j < per; j++) {
        int i = tid * per + j;
        if (i < nb) { int v = bsum[i]; bsum[i] = run; run += v; }
    }
    if (tid == 0) off[L] = total;
}

// final exclusive scan; also zeroes count[] in place (replaces a memset dispatch)
__global__ void scan3_k(int* __restrict__ count, const int* __restrict__ bsum,
                        int* __restrict__ off, int L) {
    __shared__ int s[SCAN_T];
    const int PER = SCAN_CHUNK / SCAN_T;  // 8
    int tid = threadIdx.x;
    int base = blockIdx.x * SCAN_CHUNK + tid * PER;
    int c[PER];
    int tsum = 0;
#pragma unroll
    for (int j = 0; j < PER; j++) { int i = base + j; c[j] = (i < L) ? count[i] : 0; tsum += c[j]; }
    s[tid] = tsum; __syncthreads();
    for (int o = 1; o < SCAN_T; o <<= 1) {
        int v = (tid >= o) ? s[tid - o] : 0;
        __syncthreads();
        s[tid] += v;
        __syncthreads();
    }
    int run = bsum[blockIdx.x] + s[tid] - tsum;
#pragma unroll
    for (int j = 0; j < PER; j++) {
        int i = base + j;
        if (i < L) { off[i] = run; count[i] = 0; }
        run += c[j];
    }
}

// dual-range j-major scatter: one packed 8B store per entry (pixel, weight-bits)
__global__ void scatter2_k(const int* __restrict__ osA, const float* __restrict__ wsA,
                           const int* __restrict__ offA, int* __restrict__ curA,
                           int2* __restrict__ pA, int NA, int KA,
                           const int* __restrict__ osB, const float* __restrict__ wsB,
                           const int* __restrict__ offB, int* __restrict__ curB,
                           int2* __restrict__ pB, int NB, int KB) {
    int t = blockIdx.x * blockDim.x + threadIdx.x;
    if (t < NA) {
        int j = t >> LOG2N, n = t & (NPIX - 1);
        size_t e = (size_t)n * KA + j;
        int m = osA[e];
        int p = offA[m] + atomicAdd(&curA[m], 1);
        pA[p] = make_int2(n, __float_as_int(wsA[e]));
    } else {
        t -= NA;
        if (t < NB) {
            int j = t >> LOG2N, n = t & (NPIX - 1);
            size_t e = (size_t)n * KB + j;
            int m = osB[e];
            int p = offB[m] + atomicAdd(&curB[m], 1);
            pB[p] = make_int2(n, __float_as_int(wsB[e]));
        }
    }
}

// dual-range fold of nrm into packed entry weights (once per call)
__global__ void wn2_k(int2* __restrict__ pA, const float* __restrict__ nrmA, int NA,
                      int2* __restrict__ pB, const float* __restrict__ nrmB, int NB) {
    int t = blockIdx.x * blockDim.x + threadIdx.x;
    if (t < NA) {
        int2 e = pA[t];
        e.y = __float_as_int(__int_as_float(e.y) * nrmA[e.x]);
        pA[t] = e;
    } else {
        t -= NA;
        if (t < NB) {
            int2 e = pB[t];
            e.y = __float_as_int(__int_as_float(e.y) * nrmB[e.x]);
            pB[t] = e;
        }
    }
}

// ---------------- normalization lattice (C=1, f32) ----------------
__global__ void splat_gather1_k(const int2* __restrict__ pE, const int* __restrict__ off,
                                float* __restrict__ val, int M) {
    int m = blockIdx.x * blockDim.x + threadIdx.x;
    if (m > M) return;
    float s = 0.f;
    if (m > 0) {
        int e0 = off[m], e1 = off[m + 1];
        for (int e = e0; e < e1; e++) s += __int_as_float(pE[e].y);
    }
    val[m] = s;
}

__global__ void blur1_k(const float* __restrict__ vin, float* __restrict__ vout,
                        const int* __restrict__ nbr, int M) {
    int t = blockIdx.x * blockDim.x + threadIdx.x;
    if (t > M) return;
    if (t == 0) { vout[0] = 0.f; return; }
    int2 nn = ((const int2*)nbr)[t - 1];
    vout[t] = vin[t] + 0.5f * (vin[nn.x] + vin[nn.y]);
}

__global__ void slice_norm_k(const float* __restrict__ ws, const int* __restrict__ os,
                             const float* __restrict__ val, float* __restrict__ nrm,
                             int N, int K, float alpha) {
    int n = blockIdx.x * blockDim.x + threadIdx.x;
    if (n >= N) return;
    float s = 0.f;
    for (int j = 0; j < K; j++) s += ws[(size_t)n * K + j] * val[os[(size_t)n * K + j]];
    nrm[n] = 1.f / (sqrtf(alpha * s) + 1e-20f);
}

// ---------------- f16 lattice pipeline ----------------
__global__ void splatH_k(const __half2* __restrict__ Qh, const int2* __restrict__ pE,
                         const int* __restrict__ off, __half2* __restrict__ val, int M) {
    int m = blockIdx.x * blockDim.x + threadIdx.x;
    if (m > M) return;
    float acc[2 * CP];
#pragma unroll
    for (int i = 0; i < 2 * CP; i++) acc[i] = 0.f;
    if (m > 0) {
        int e0 = off[m], e1 = off[m + 1];
        for (int e = e0; e < e1; e++) {
            int2 ent = pE[e];
            float w = __int_as_float(ent.y);
            const __half2* qp = Qh + (size_t)ent.x * CP;
#pragma unroll
            for (int i = 0; i < CP; i++) {
                float2 q = __half22float2(qp[i]);
                acc[2 * i]     += w * q.x;
                acc[2 * i + 1] += w * q.y;
            }
        }
    }
    __half2* vp = val + (size_t)m * CP;
#pragma unroll
    for (int i = 0; i < CP; i++)
        vp[i] = __floats2half2_rn(acc[2 * i], acc[2 * i + 1]);
}

// single blur sweep: thread per (row, half2-pair)
__global__ void blurH_k(const __half2* __restrict__ vin, __half2* __restrict__ vout,
                        const int* __restrict__ nbr, int M) {
    int t = blockIdx.x * blockDim.x + threadIdx.x;
    int total = (M + 1) * CP;
    if (t >= total) return;
    int m = t / CP;
    int cp = t - m * CP;
    if (m == 0) { vout[t] = __floats2half2_rn(0.f, 0.f); return; }
    int2 nn = ((const int2*)nbr)[m - 1];
    float2 a = __half22float2(vin[t]);
    float2 b = __half22float2(vin[(size_t)nn.x * CP + cp]);
    float2 c = __half22float2(vin[(size_t)nn.y * CP + cp]);
    vout[t] = __floats2half2_rn(a.x + 0.5f * (b.x + c.x), a.y + 0.5f * (b.y + c.y));
}

// fused double blur: direction A then direction B in one pass.
__global__ void blurH2_k(const __half2* __restrict__ vin, __half2* __restrict__ vout,
                         const int* __restrict__ nbrA, const int* __restrict__ nbrB, int M) {
    int m = blockIdx.x * blockDim.x + threadIdx.x;
    if (m > M) return;
    __half2* op = vout + (size_t)m * CP;
    if (m == 0) {
        __half2 z = __floats2half2_rn(0.f, 0.f);
#pragma unroll
        for (int i = 0; i < CP; i++) op[i] = z;
        return;
    }
    float acc[2 * CP];
#pragma unroll
    for (int i = 0; i < 2 * CP; i++) acc[i] = 0.f;
    int2 nbB = ((const int2*)nbrB)[m - 1];

    {
        int2 na = ((const int2*)nbrA)[m - 1];
        const __half2* p0 = vin + (size_t)m * CP;
        const __half2* p1 = vin + (size_t)na.x * CP;
        const __half2* p2 = vin + (size_t)na.y * CP;
#pragma unroll
        for (int i = 0; i < CP; i++) {
            float2 a = __half22float2(p0[i]);
            float2 b = __half22float2(p1[i]);
            float2 c = __half22float2(p2[i]);
            acc[2 * i]     += a.x + 0.5f * (b.x + c.x);
            acc[2 * i + 1] += a.y + 0.5f * (b.y + c.y);
        }
    }
    if (nbB.x > 0) {
        int2 na = ((const int2*)nbrA)[nbB.x - 1];
        const __half2* p0 = vin + (size_t)nbB.x * CP;
        const __half2* p1 = vin + (size_t)na.x * CP;
        const __half2* p2 = vin + (size_t)na.y * CP;
#pragma unroll
        for (int i = 0; i < CP; i++) {
            float2 a = __half22float2(p0[i]);
            float2 b = __half22float2(p1[i]);
            float2 c = __half22float2(p2[i]);
            acc[2 * i]     += 0.5f * (a.x + 0.5f * (b.x + c.x));
            acc[2 * i + 1] += 0.5f * (a.y + 0.5f * (b.y + c.y));
        }
    }
    if (nbB.y > 0) {
        int2 na = ((const int2*)nbrA)[nbB.y - 1];
        const __half2* p0 = vin + (size_t)nbB.y * CP;
        const __half2* p1 = vin + (size_t)na.x * CP;
        const __half2* p2 = vin + (size_t)na.y * CP;
#pragma unroll
        for (int i = 0; i < CP; i++) {
            float2 a = __half22float2(p0[i]);
            float2 b = __half22float2(p1[i]);
            float2 c = __half22float2(p2[i]);
            acc[2 * i]     += 0.5f * (a.x + 0.5f * (b.x + c.x));
            acc[2 * i + 1] += 0.5f * (a.y + 0.5f * (b.y + c.y));
        }
    }
#pragma unroll
    for (int i = 0; i < CP; i++)
        op[i] = __floats2half2_rn(acc[2 * i], acc[2 * i + 1]);
}

// ---------------- softmax kernels ----------------
__global__ void softmax_init_k(const float* __restrict__ u, __half2* __restrict__ Qh,
                               __half2* __restrict__ uh, int N) {
    int n = blockIdx.x * blockDim.x + threadIdx.x;
    if (n >= N) return;
    const float* up = u + (size_t)n * NC;
    float uv[2 * CP], v[2 * CP];
    float mx = -1e30f;
#pragma unroll
    for (int c = 0; c < NC; c++) { uv[c] = up[c]; v[c] = -uv[c]; mx = fmaxf(mx, v[c]); }
    float s = 0.f;
#pragma unroll
    for (int c = 0; c < NC; c++) { v[c] = __expf(v[c] - mx); s += v[c]; }
    float inv = 1.f / s;
#pragma unroll
    for (int c = 0; c < NC; c++) v[c] *= inv;
    v[NC] = 0.f; uv[NC] = 0.f;
    __half2* hp = Qh + (size_t)n * CP;
    __half2* uhp = uh + (size_t)n * CP;
#pragma unroll
    for (int i = 0; i < CP; i++) {
        hp[i]  = __floats2half2_rn(v[2 * i], v[2 * i + 1]);
        uhp[i] = __floats2half2_rn(uv[2 * i], uv[2 * i + 1]);
    }
}

// fused: slice bilateral + slice spatial + softmax update.
__global__ void slice_update_k(const __half2* __restrict__ uh,
                               const int* __restrict__ os_bi, const float* __restrict__ ws_bi,
                               const __half2* __restrict__ vbi, const float* __restrict__ nrm_bi,
                               const int* __restrict__ os_sp, const float* __restrict__ ws_sp,
                               const __half2* __restrict__ vsp, const float* __restrict__ nrm_sp,
                               float* __restrict__ Q, __half2* __restrict__ Qh,
                               int N, float abi, float asp, int final_it) {
    int n = blockIdx.x * blockDim.x + threadIdx.x;
    if (n >= N) return;
    float acc[2 * CP];
#pragma unroll
    for (int i = 0; i < 2 * CP; i++) acc[i] = 0.f;
    for (int j = 0; j < 6; j++) {
        float w = ws_bi[(size_t)n * 6 + j];
        const __half2* vp = vbi + (size_t)os_bi[(size_t)n * 6 + j] * CP;
#pragma unroll
        for (int i = 0; i < CP; i++) {
            float2 f = __half22float2(vp[i]);
            acc[2 * i]     += w * f.x;
            acc[2 * i + 1] += w * f.y;
        }
    }
    float sb = 10.f * abi * nrm_bi[n];
#pragma unroll
    for (int i = 0; i < 2 * CP; i++) acc[i] *= sb;
    float ss = 3.f * asp * nrm_sp[n];
    for (int j = 0; j < 3; j++) {
        float w = ss * ws_sp[(size_t)n * 3 + j];
        const __half2* vp = vsp + (size_t)os_sp[(size_t)n * 3 + j] * CP;
#pragma unroll
        for (int i = 0; i < CP; i++) {
            float2 f = __half22float2(vp[i]);
            acc[2 * i]     += w * f.x;
            acc[2 * i + 1] += w * f.y;
        }
    }
    const __half2* uhp = uh + (size_t)n * CP;
#pragma unroll
    for (int i = 0; i < CP; i++) {
        float2 uu = __half22float2(uhp[i]);
        acc[2 * i]     -= uu.x;
        acc[2 * i + 1] -= uu.y;
    }
    float mx = -1e30f;
#pragma unroll
    for (int c = 0; c < NC; c++) mx = fmaxf(mx, acc[c]);
    float s = 0.f;
#pragma unroll
    for (int c = 0; c < NC; c++) { acc[c] = __expf(acc[c] - mx); s += acc[c]; }
    float inv = 1.f / s;
#pragma unroll
    for (int c = 0; c < NC; c++) acc[c] *= inv;
    acc[NC] = 0.f;
    if (final_it) {
        float* qp = Q + (size_t)n * NC;
#pragma unroll
        for (int c = 0; c < NC; c++) qp[c] = acc[c];
    } else {
        __half2* hp = Qh + (size_t)n * CP;
#pragma unroll
        for (int i = 0; i < CP; i++) hp[i] = __floats2half2_rn(acc[2 * i], acc[2 * i + 1]);
    }
}

extern "C" void kernel_launch(void* const* d_in, const int* in_sizes, int n_in,
                              void* d_out, int out_size, void* d_ws, size_t ws_size,
                              hipStream_t stream) {
    const float* unary  = (const float*)d_in[0];
    const float* ws_bi  = (const float*)d_in[1];
    const float* ws_sp  = (const float*)d_in[2];
    const int*   os_bi  = (const int*)d_in[3];
    const int*   os_sp  = (const int*)d_in[4];
    const int*   nbr_bi = (const int*)d_in[5];
    const int*   nbr_sp = (const int*)d_in[6];
    float* Q = (float*)d_out;

    const int N = NPIX, Kbi = 6, Ksp = 3;
    const int Mbi = in_sizes[5] / (Kbi * 2);
    const int Msp = in_sizes[6] / (Ksp * 2);
    const int NKbi = N * Kbi, NKsp = N * Ksp;
    const float alpha_bi = 32.f / 33.f;
    const float alpha_sp = 0.8f;

    // ---- workspace layout (4-byte units) ----
    char* basec = (char*)d_ws;
    size_t off4 = 0;
    auto allocf = [&](size_t nf) { float* p = (float*)basec + off4; off4 += (nf + 3) & ~(size_t)3; return p; };
    auto alloci = [&](size_t ni) { int* p = (int*)basec + off4; off4 += (ni + 3) & ~(size_t)3; return p; };
    auto alloch2 = [&](size_t nh2) { __half2* p = (__half2*)((float*)basec + off4); off4 += (nh2 + 3) & ~(size_t)3; return p; };
    auto alloci2 = [&](size_t ni2) { int2* p = (int2*)((float*)basec + off4); off4 += 2 * ni2; return p; };

    float*   nrm_bi = allocf(N);
    float*   nrm_sp = allocf(N);
    __half2* Qh     = alloch2((size_t)N * CP);
    __half2* uh     = alloch2((size_t)N * CP);
    int2*    pE_bi  = alloci2(NKbi);
    int*     off_bi = alloci(Mbi + 2);
    int2*    pE_sp  = alloci2(NKsp);
    int*     off_sp = alloci(Msp + 2);
    int*     cur_bi = alloci((size_t)(Mbi + 1) + (Msp + 1));
    int*     cur_sp = cur_bi + (Mbi + 1);
    int*     bsum   = alloci(4096);
    __half2* vbiA   = alloch2((size_t)(Mbi + 1) * CP);
    __half2* vbiB   = alloch2((size_t)(Mbi + 1) * CP);
    __half2* vspA   = alloch2((size_t)(Msp + 1) * CP);
    __half2* vspB   = alloch2((size_t)(Msp + 1) * CP);
    float* nv_biA = (float*)vbiA;
    float* nv_biB = (float*)vbiB;
    float* nv_spA = (float*)vspA;
    float* nv_spB = (float*)vspB;

    const int B = 256;
    const int nb_bi = cdiv_l(Mbi + 1, SCAN_CHUNK);
    const int nb_sp = cdiv_l(Msp + 1, SCAN_CHUNK);
    const size_t cur_span = ((size_t)(Mbi + 1) + (Msp + 1)) * sizeof(int);

    // ---- CSR build (both lattices), j-major ----
    hipMemsetAsync(cur_bi, 0, cur_span, stream);
    hist2_k<<<cdiv_l((long)NKbi + NKsp, B), B, 0, stream>>>(
        os_bi, cur_bi, NKbi, Kbi, os_sp, cur_sp, NKsp, Ksp);
    scan1_k<<<nb_bi, SCAN_T, 0, stream>>>(cur_bi, bsum, Mbi + 1);
    scan2_k<<<1, SCAN_T, 0, stream>>>(bsum, nb_bi, off_bi, Mbi + 1);
    scan3_k<<<nb_bi, SCAN_T, 0, stream>>>(cur_bi, bsum, off_bi, Mbi + 1);
    scan1_k<<<nb_sp, SCAN_T, 0, stream>>>(cur_sp, bsum, Msp + 1);
    scan2_k<<<1, SCAN_T, 0, stream>>>(bsum, nb_sp, off_sp, Msp + 1);
    scan3_k<<<nb_sp, SCAN_T, 0, stream>>>(cur_sp, bsum, off_sp, Msp + 1);
    scatter2_k<<<cdiv_l((long)NKbi + NKsp, B), B, 0, stream>>>(
        os_bi, ws_bi, off_bi, cur_bi, pE_bi, NKbi, Kbi,
        os_sp, ws_sp, off_sp, cur_sp, pE_sp, NKsp, Ksp);

    // ---- bilateral normalization (C=1, f32; uses vbi regions) ----
    splat_gather1_k<<<cdiv_l(Mbi + 1, B), B, 0, stream>>>(pE_bi, off_bi, nv_biA, Mbi);
    {
        float* s = nv_biA; float* d = nv_biB;
        for (int j = 0; j < Kbi; j++) {
            blur1_k<<<cdiv_l(Mbi + 1, B), B, 0, stream>>>(s, d, nbr_bi + (size_t)j * Mbi * 2, Mbi);
            float* t = s; s = d; d = t;
        }
        slice_norm_k<<<cdiv_l(N, B), B, 0, stream>>>(ws_bi, os_bi, s, nrm_bi, N, Kbi, alpha_bi);
    }

    // ---- spatial normalization (C=1, f32; uses vsp regions) ----
    splat_gather1_k<<<cdiv_l(Msp + 1, B), B, 0, stream>>>(pE_sp, off_sp, nv_spA, Msp);
    {
        float* s = nv_spA; float* d = nv_spB;
        for (int j = 0; j < Ksp; j++) {
            blur1_k<<<cdiv_l(Msp + 1, B), B, 0, stream>>>(s, d, nbr_sp + (size_t)j * Msp * 2, Msp);
            float* t = s; s = d; d = t;
        }
        slice_norm_k<<<cdiv_l(N, B), B, 0, stream>>>(ws_sp, os_sp, s, nrm_sp, N, Ksp, alpha_sp);
    }

    // ---- fold nrm into packed entry weights ----
    wn2_k<<<cdiv_l((long)NKbi + NKsp, B), B, 0, stream>>>(pE_bi, nrm_bi, NKbi, pE_sp, nrm_sp, NKsp);

    // ---- Qh = softmax(-u) f16; uh = u f16 ----
    softmax_init_k<<<cdiv_l(N, B), B, 0, stream>>>(unary, Qh, uh, N);

    // ---- mean-field iterations ----
    for (int it = 0; it < 5; it++) {
        splatH_k<<<cdiv_l(Mbi + 1, B), B, 0, stream>>>(Qh, pE_bi, off_bi, vbiA, Mbi);
        blurH2_k<<<cdiv_l(Mbi + 1, B), B, 0, stream>>>(
            vbiA, vbiB, nbr_bi + (size_t)0 * Mbi * 2, nbr_bi + (size_t)1 * Mbi * 2, Mbi);
        blurH2_k<<<cdiv_l(Mbi + 1, B), B, 0, stream>>>(
            vbiB, vbiA, nbr_bi + (size_t)2 * Mbi * 2, nbr_bi + (size_t)3 * Mbi * 2, Mbi);
        blurH2_k<<<cdiv_l(Mbi + 1, B), B, 0, stream>>>(
            vbiA, vbiB, nbr_bi + (size_t)4 * Mbi * 2, nbr_bi + (size_t)5 * Mbi * 2, Mbi);
        splatH_k<<<cdiv_l(Msp + 1, B), B, 0, stream>>>(Qh, pE_sp, off_sp, vspA, Msp);
        blurH2_k<<<cdiv_l(Msp + 1, B), B, 0, stream>>>(
            vspA, vspB, nbr_sp + (size_t)0 * Msp * 2, nbr_sp + (size_t)1 * Msp * 2, Msp);
        blurH_k<<<cdiv_l((long)(Msp + 1) * CP, B), B, 0, stream>>>(
            vspB, vspA, nbr_sp + (size_t)2 * Msp * 2, Msp);
        slice_update_k<<<cdiv_l(N, B), B, 0, stream>>>(
            uh, os_bi, ws_bi, vbiB, nrm_bi, os_sp, ws_sp, vspA, nrm_sp,
            Q, Qh, N, alpha_bi, alpha_sp, it == 4 ? 1 : 0);
    }
}